// Round 4
// baseline (2836.765 us; speedup 1.0000x reference)
//
#include <hip/hip_runtime.h>
#include <hip/hip_bf16.h>
#include <cmath>

#define B_ 2
#define L_ 1024
#define DM 1024
#define DI 2048
#define NS 16
#define RR 64
#define KC 4

// C[M,N] = A[M,K] (row-major, lda) * W rows [wRowOff, wRowOff+N) of W[*,K] (row-major, ldw)
// flip: remap A row m -> b*Lseq + (Lseq-1-l) within each batch of Lseq rows
__global__ void gemm_bt(const float* __restrict__ A, int lda,
                        const float* __restrict__ W, int ldw, int wRowOff,
                        float* __restrict__ C, int ldc,
                        int M, int N, int K, int Lseq, int flip) {
    __shared__ float As[16][65];
    __shared__ float Ws[16][65];
    const int tid = threadIdx.x;           // 256
    const int m0 = blockIdx.y * 64;
    const int n0 = blockIdx.x * 64;
    const int tx = tid % 16, ty = tid / 16;
    float acc[4][4] = {};

    for (int k0 = 0; k0 < K; k0 += 16) {
#pragma unroll
        for (int j = 0; j < 4; ++j) {
            int e = tid + 256 * j;
            int r = e >> 4, kk = e & 15;
            int gm = m0 + r;
            float v = 0.f;
            if (gm < M) {
                int srow = gm;
                if (flip) { int bb = gm / Lseq, ll = gm % Lseq; srow = bb * Lseq + (Lseq - 1 - ll); }
                v = A[(size_t)srow * lda + k0 + kk];
            }
            As[kk][r] = v;
        }
#pragma unroll
        for (int j = 0; j < 4; ++j) {
            int e = tid + 256 * j;
            int r = e >> 4, kk = e & 15;
            int gn = n0 + r;
            float v = 0.f;
            if (gn < N) v = W[(size_t)(gn + wRowOff) * ldw + k0 + kk];
            Ws[kk][r] = v;
        }
        __syncthreads();
#pragma unroll
        for (int kk = 0; kk < 16; ++kk) {
            float a[4], w[4];
#pragma unroll
            for (int i = 0; i < 4; ++i) a[i] = As[kk][ty + 16 * i];
#pragma unroll
            for (int i = 0; i < 4; ++i) w[i] = Ws[kk][tx + 16 * i];
#pragma unroll
            for (int i = 0; i < 4; ++i)
#pragma unroll
                for (int j = 0; j < 4; ++j) acc[i][j] += a[i] * w[j];
        }
        __syncthreads();
    }
#pragma unroll
    for (int i = 0; i < 4; ++i) {
        int gm = m0 + ty + 16 * i;
        if (gm >= M) continue;
#pragma unroll
        for (int j = 0; j < 4; ++j) {
            int gn = n0 + tx + 16 * j;
            if (gn >= N) continue;
            C[(size_t)gm * ldc + gn] = acc[i][j];
        }
    }
}

// depthwise causal conv (K=4) + bias + SiLU
__global__ void conv_silu(const float* __restrict__ x,
                          const float* __restrict__ w,
                          const float* __restrict__ bias,
                          float* __restrict__ y, int total) {
    int idx = blockIdx.x * blockDim.x + threadIdx.x;
    if (idx >= total) return;
    int d = idx % DI;
    int l = (idx / DI) % L_;
    float acc = bias[d];
#pragma unroll
    for (int k = 0; k < KC; ++k) {
        int ls = l + k - (KC - 1);
        if (ls >= 0) acc += x[idx + (size_t)(ls - l) * DI] * w[d * KC + k];
    }
    float s = 1.f / (1.f + __expf(-acc));
    y[idx] = acc * s;
}

// delta = softplus(dtmat + 2*bdt), in place
__global__ void delta_softplus(float* __restrict__ dtm,
                               const float* __restrict__ bdt, int total) {
    int idx = blockIdx.x * blockDim.x + threadIdx.x;
    if (idx >= total) return;
    int d = idx % DI;
    float x = dtm[idx] + 2.f * bdt[d];
    dtm[idx] = (x > 20.f) ? x : log1pf(__expf(x));
}

// selective scan: one thread per (b,d), h[16] in regs. y may alias delta (in-order RW).
__global__ void scan_kernel(const float* __restrict__ u, const float* __restrict__ delta,
                            const float* __restrict__ dbl,
                            const float* __restrict__ A_log,
                            const float* __restrict__ Dv,
                            float* __restrict__ y) {
    int d = blockIdx.x * blockDim.x + threadIdx.x;  // 0..DI-1
    int bb = blockIdx.y;
    float Av[NS], h[NS];
#pragma unroll
    for (int n = 0; n < NS; ++n) {
        Av[n] = -expf(A_log[d * NS + n]);
        h[n] = 0.f;
    }
    float Dd = Dv[d];
    const float* up = u + (size_t)bb * L_ * DI + d;
    const float* dp = delta + (size_t)bb * L_ * DI + d;
    const float* blp = dbl + (size_t)bb * L_ * 96;
    float* yp = y + (size_t)bb * L_ * DI + d;
    for (int l = 0; l < L_; ++l) {
        float del = dp[(size_t)l * DI];
        float ul = up[(size_t)l * DI];
        float du = del * ul;
        const float* Brow = blp + l * 96 + RR;
        float acc = 0.f;
#pragma unroll
        for (int n = 0; n < NS; ++n) {
            float dA = __expf(del * Av[n]);
            h[n] = dA * h[n] + du * Brow[n];
            acc += h[n] * Brow[NS + n];
        }
        yp[(size_t)l * DI] = acc + ul * Dd;
    }
}

// g = (y_f + flip(y_b)) * silu(z); g *= rsqrt(mean(g^2)+eps)*norm_w. g may alias yf.
__global__ void combine_rms(const float* __restrict__ yf, const float* __restrict__ yb,
                            const float* __restrict__ z,
                            const float* __restrict__ nw,
                            float* __restrict__ g) {
    int row = blockIdx.x;  // b*L + l
    int bb = row / L_, l = row % L_;
    int tid = threadIdx.x;  // 256
    size_t base = (size_t)row * DI;
    size_t baseb = ((size_t)bb * L_ + (L_ - 1 - l)) * DI;
    float gv[8];
    float ss = 0.f;
#pragma unroll
    for (int j = 0; j < 8; ++j) {
        int d = tid + j * 256;
        float yy = yf[base + d] + yb[baseb + d];
        float zz = z[base + d];
        float s = zz / (1.f + __expf(-zz));
        float gg = yy * s;
        gv[j] = gg;
        ss += gg * gg;
    }
#pragma unroll
    for (int off = 32; off > 0; off >>= 1) ss += __shfl_down(ss, off, 64);
    __shared__ float red[4];
    if ((tid & 63) == 0) red[tid >> 6] = ss;
    __syncthreads();
    float tot = red[0] + red[1] + red[2] + red[3];
    float rms = rsqrtf(tot / (float)DI + 1e-5f);
#pragma unroll
    for (int j = 0; j < 8; ++j) {
        int d = tid + j * 256;
        g[base + d] = gv[j] * rms * nw[d];
    }
}

extern "C" void kernel_launch(void* const* d_in, const int* in_sizes, int n_in,
                              void* d_out, int out_size, void* d_ws, size_t ws_size,
                              hipStream_t stream) {
    const float* a      = (const float*)d_in[0];
    const float* b      = (const float*)d_in[1];
    const float* Wi     = (const float*)d_in[2];
    const float* conv_w = (const float*)d_in[3];
    const float* conv_b = (const float*)d_in[4];
    const float* Wx     = (const float*)d_in[5];
    const float* Wdt    = (const float*)d_in[6];
    const float* bdt    = (const float*)d_in[7];
    const float* A_log  = (const float*)d_in[8];
    const float* Dvec   = (const float*)d_in[9];
    const float* conv_w_b = (const float*)d_in[10];
    const float* conv_b_b = (const float*)d_in[11];
    const float* Wx_b   = (const float*)d_in[12];
    const float* Wdt_b  = (const float*)d_in[13];
    const float* bdt_b  = (const float*)d_in[14];
    const float* A_log_b = (const float*)d_in[15];
    const float* Dvec_b = (const float*)d_in[16];
    const float* Wo     = (const float*)d_in[17];
    const float* nw     = (const float*)d_in[18];
    float* out = (float*)d_out;   // reference output dtype is float32

    const int M = B_ * L_;              // 2048
    const size_t BLD = (size_t)M * DI;  // 4194304 floats
    float* f = (float*)d_ws;
    float* B1 = f;                      // x_f -> delta_f -> y_f -> g
    float* B2 = f + BLD;                // c_f -> x_b -> delta_b -> y_b
    float* B3 = f + 2 * BLD;            // c_b -> z
    float* dblf = f + 3 * BLD;
    float* dblb = dblf + (size_t)M * 96;

    dim3 blk(256);
    const int totBLD = M * DI;

    // ---- forward branch ----
    gemm_bt<<<dim3(DI / 64, M / 64), blk, 0, stream>>>(
        a, DM, Wi, DM, 0, B1, DI, M, DI, DM, L_, 0);
    conv_silu<<<dim3(totBLD / 256), blk, 0, stream>>>(B1, conv_w, conv_b, B2, totBLD);
    gemm_bt<<<dim3(2, M / 64), blk, 0, stream>>>(
        B2, DI, Wx, DI, 0, dblf, 96, M, 96, DI, L_, 0);
    gemm_bt<<<dim3(DI / 64, M / 64), blk, 0, stream>>>(
        dblf, 96, Wdt, RR, 0, B1, DI, M, DI, RR, L_, 0);
    delta_softplus<<<dim3(totBLD / 256), blk, 0, stream>>>(B1, bdt, totBLD);
    scan_kernel<<<dim3(DI / 256, B_), blk, 0, stream>>>(B2, B1, dblf, A_log, Dvec, B1);

    // ---- backward branch ----
    gemm_bt<<<dim3(DI / 64, M / 64), blk, 0, stream>>>(
        b, DM, Wi, DM, 0, B2, DI, M, DI, DM, L_, 1);
    conv_silu<<<dim3(totBLD / 256), blk, 0, stream>>>(B2, conv_w_b, conv_b_b, B3, totBLD);
    gemm_bt<<<dim3(2, M / 64), blk, 0, stream>>>(
        B3, DI, Wx_b, DI, 0, dblb, 96, M, 96, DI, L_, 0);
    gemm_bt<<<dim3(DI / 64, M / 64), blk, 0, stream>>>(
        dblb, 96, Wdt_b, RR, 0, B2, DI, M, DI, RR, L_, 0);
    delta_softplus<<<dim3(totBLD / 256), blk, 0, stream>>>(B2, bdt_b, totBLD);
    scan_kernel<<<dim3(DI / 256, B_), blk, 0, stream>>>(B3, B2, dblb, A_log_b, Dvec_b, B2);

    // ---- combine ----
    // z = a @ Wi[DI:2*DI].T -> B3 (c_b dead)
    gemm_bt<<<dim3(DI / 64, M / 64), blk, 0, stream>>>(
        a, DM, Wi, DM, DI, B3, DI, M, DI, DM, L_, 0);
    combine_rms<<<dim3(M), blk, 0, stream>>>(B1, B2, B3, nw, B1);
    // out = g @ Wo.T (fp32 out)
    gemm_bt<<<dim3(DM / 64, M / 64), blk, 0, stream>>>(
        B1, DI, Wo, DI, 0, out, DM, M, DM, DI, L_, 0);
}

// Round 5
// 1116.686 us; speedup vs baseline: 2.5403x; 2.5403x over previous
//
#include <hip/hip_runtime.h>
#include <hip/hip_bf16.h>
#include <cmath>

#define B_ 2
#define L_ 1024
#define DM 1024
#define DI 2048
#define NS 16
#define RR 64
#define KC 4
#define NCH 32
#define CL (L_ / NCH)   // 32

// C[M,N] = A[M,K] (row-major, lda) * W rows [wRowOff, wRowOff+N) of W[*,K] (row-major, ldw)
// flip: remap A row m -> b*Lseq + (Lseq-1-l) within each batch of Lseq rows
// M must be a multiple of 64; N a multiple of 4; K a multiple of 16.
__global__ void gemm_bt(const float* __restrict__ A, int lda,
                        const float* __restrict__ W, int ldw, int wRowOff,
                        float* __restrict__ C, int ldc,
                        int M, int N, int K, int Lseq, int flip) {
    // pad 68: write bank = ((k)*68 + m) % 32 = (4k + m) % 32 -> exact 2-way (free)
    __shared__ float As[16][68];
    __shared__ float Ws[16][68];
    const int tid = threadIdx.x;          // 256
    const int m0 = blockIdx.y * 64;
    const int n0 = blockIdx.x * 64;
    const int tx = tid & 15, ty = tid >> 4;
    const int lr = tid >> 2;              // staging row 0..63
    const int lc = (tid & 3) << 2;        // staging k-offset 0,4,8,12

    int arow = m0 + lr;
    int srow = arow;
    if (flip) { int bb = arow / Lseq, ll = arow % Lseq; srow = bb * Lseq + (Lseq - 1 - ll); }
    const float* Aptr = A + (size_t)srow * lda + lc;
    int wrow = n0 + lr;
    const bool wok = wrow < N;
    const float* Wptr = W + (size_t)(wrow + wRowOff) * ldw + lc;

    float acc[4][4] = {};

    for (int k0 = 0; k0 < K; k0 += 16) {
        float4 av = *(const float4*)(Aptr + k0);
        float4 wv = make_float4(0.f, 0.f, 0.f, 0.f);
        if (wok) wv = *(const float4*)(Wptr + k0);
        __syncthreads();   // previous compute done reading LDS
        As[lc + 0][lr] = av.x; As[lc + 1][lr] = av.y;
        As[lc + 2][lr] = av.z; As[lc + 3][lr] = av.w;
        Ws[lc + 0][lr] = wv.x; Ws[lc + 1][lr] = wv.y;
        Ws[lc + 2][lr] = wv.z; Ws[lc + 3][lr] = wv.w;
        __syncthreads();
#pragma unroll
        for (int kk = 0; kk < 16; ++kk) {
            float4 a4 = *(const float4*)&As[kk][ty * 4];   // b128, 4-addr broadcast
            float4 w4 = *(const float4*)&Ws[kk][tx * 4];   // b128, 2-way (free)
            float ar[4] = {a4.x, a4.y, a4.z, a4.w};
            float wr[4] = {w4.x, w4.y, w4.z, w4.w};
#pragma unroll
            for (int i = 0; i < 4; ++i)
#pragma unroll
                for (int j = 0; j < 4; ++j) acc[i][j] += ar[i] * wr[j];
        }
    }
#pragma unroll
    for (int i = 0; i < 4; ++i) {
        int gm = m0 + ty * 4 + i;
        int gn = n0 + tx * 4;
        if (gn < N) {
            float4 st = make_float4(acc[i][0], acc[i][1], acc[i][2], acc[i][3]);
            *(float4*)&C[(size_t)gm * ldc + gn] = st;
        }
    }
}

// depthwise causal conv (K=4) + bias + SiLU
__global__ void conv_silu(const float* __restrict__ x,
                          const float* __restrict__ w,
                          const float* __restrict__ bias,
                          float* __restrict__ y, int total) {
    int idx = blockIdx.x * blockDim.x + threadIdx.x;
    if (idx >= total) return;
    int d = idx % DI;
    int l = (idx / DI) % L_;
    float acc = bias[d];
#pragma unroll
    for (int k = 0; k < KC; ++k) {
        int ls = l + k - (KC - 1);
        if (ls >= 0) acc += x[idx + (size_t)(ls - l) * DI] * w[d * KC + k];
    }
    float s = 1.f / (1.f + __expf(-acc));
    y[idx] = acc * s;
}

__device__ __forceinline__ float softplus2(float raw, float bd2) {
    float x = raw + bd2;
    return (x > 20.f) ? x : log1pf(__expf(x));
}

// Pass A: per-chunk P = prod(dA), S = local scan state from h=0. Softplus folded.
// layout of P/S: ((b*NCH + c)*NS + n)*DI + d   (d fastest -> coalesced)
__global__ void scan_chunk(const float* __restrict__ u, const float* __restrict__ dtraw,
                           const float* __restrict__ bdt,
                           const float* __restrict__ dbl,
                           const float* __restrict__ A_log,
                           float* __restrict__ Pbuf, float* __restrict__ Sbuf) {
    int d = blockIdx.x * blockDim.x + threadIdx.x;   // 0..DI-1
    int bb = blockIdx.y, c = blockIdx.z;
    float Av[NS], P[NS], S[NS];
#pragma unroll
    for (int n = 0; n < NS; ++n) {
        Av[n] = -__expf(A_log[d * NS + n]);
        P[n] = 1.f; S[n] = 0.f;
    }
    float bd2 = 2.f * bdt[d];
    const int l0 = c * CL;
    const float* up = u + ((size_t)bb * L_ + l0) * DI + d;
    const float* dp = dtraw + ((size_t)bb * L_ + l0) * DI + d;
    const float* blp = dbl + ((size_t)bb * L_ + l0) * 96 + RR;
    for (int l = 0; l < CL; ++l) {
        float del = softplus2(dp[(size_t)l * DI], bd2);
        float du = del * up[(size_t)l * DI];
        const float* Brow = blp + l * 96;
#pragma unroll
        for (int n = 0; n < NS; ++n) {
            float dA = __expf(del * Av[n]);
            P[n] *= dA;
            S[n] = dA * S[n] + du * Brow[n];
        }
    }
    size_t pb = ((size_t)(bb * NCH + c) * NS) * DI + d;
#pragma unroll
    for (int n = 0; n < NS; ++n) {
        Pbuf[pb + (size_t)n * DI] = P[n];
        Sbuf[pb + (size_t)n * DI] = S[n];
    }
}

// Pass B: sequentially compose chunk states; overwrite Pbuf[c] with h_start[c].
__global__ void scan_combine(float* __restrict__ Pbuf, const float* __restrict__ Sbuf) {
    int idx = blockIdx.x * blockDim.x + threadIdx.x;  // 0..B_*DI-1
    int bb = idx / DI, d = idx % DI;
    float h[NS];
#pragma unroll
    for (int n = 0; n < NS; ++n) h[n] = 0.f;
    for (int c = 0; c < NCH; ++c) {
        size_t pb = ((size_t)(bb * NCH + c) * NS) * DI + d;
#pragma unroll
        for (int n = 0; n < NS; ++n) {
            size_t o = pb + (size_t)n * DI;
            float P = Pbuf[o], S = Sbuf[o];
            Pbuf[o] = h[n];              // h_start for this chunk
            h[n] = P * h[n] + S;
        }
    }
}

// Pass C: re-run chunk from correct h_start, emit y. y may alias dtraw (in-order RW per thread).
__global__ void scan_apply(const float* __restrict__ u, const float* dtraw,
                           const float* __restrict__ bdt,
                           const float* __restrict__ dbl,
                           const float* __restrict__ A_log,
                           const float* __restrict__ Dv,
                           const float* __restrict__ Hbuf,
                           float* y) {
    int d = blockIdx.x * blockDim.x + threadIdx.x;
    int bb = blockIdx.y, c = blockIdx.z;
    float Av[NS], h[NS];
    size_t pb = ((size_t)(bb * NCH + c) * NS) * DI + d;
#pragma unroll
    for (int n = 0; n < NS; ++n) {
        Av[n] = -__expf(A_log[d * NS + n]);
        h[n] = Hbuf[pb + (size_t)n * DI];
    }
    float bd2 = 2.f * bdt[d];
    float Dd = Dv[d];
    const int l0 = c * CL;
    const float* up = u + ((size_t)bb * L_ + l0) * DI + d;
    const float* dp = dtraw + ((size_t)bb * L_ + l0) * DI + d;
    const float* blp = dbl + ((size_t)bb * L_ + l0) * 96 + RR;
    float* yp = y + ((size_t)bb * L_ + l0) * DI + d;
    for (int l = 0; l < CL; ++l) {
        float del = softplus2(dp[(size_t)l * DI], bd2);
        float ul = up[(size_t)l * DI];
        float du = del * ul;
        const float* Brow = blp + l * 96;
        float acc = 0.f;
#pragma unroll
        for (int n = 0; n < NS; ++n) {
            float dA = __expf(del * Av[n]);
            h[n] = dA * h[n] + du * Brow[n];
            acc += h[n] * Brow[NS + n];
        }
        yp[(size_t)l * DI] = acc + ul * Dd;
    }
}

// g = (y_f + flip(y_b)) * silu(z); g *= rsqrt(mean(g^2)+eps)*norm_w. g may alias yf.
__global__ void combine_rms(const float* __restrict__ yf, const float* __restrict__ yb,
                            const float* __restrict__ z,
                            const float* __restrict__ nw,
                            float* __restrict__ g) {
    int row = blockIdx.x;  // b*L + l
    int bb = row / L_, l = row % L_;
    int tid = threadIdx.x;  // 256
    size_t base = (size_t)row * DI;
    size_t baseb = ((size_t)bb * L_ + (L_ - 1 - l)) * DI;
    float gv[8];
    float ss = 0.f;
#pragma unroll
    for (int j = 0; j < 8; ++j) {
        int d = tid + j * 256;
        float yy = yf[base + d] + yb[baseb + d];
        float zz = z[base + d];
        float s = zz / (1.f + __expf(-zz));
        float gg = yy * s;
        gv[j] = gg;
        ss += gg * gg;
    }
#pragma unroll
    for (int off = 32; off > 0; off >>= 1) ss += __shfl_down(ss, off, 64);
    __shared__ float red[4];
    if ((tid & 63) == 0) red[tid >> 6] = ss;
    __syncthreads();
    float tot = red[0] + red[1] + red[2] + red[3];
    float rms = rsqrtf(tot / (float)DI + 1e-5f);
#pragma unroll
    for (int j = 0; j < 8; ++j) {
        int d = tid + j * 256;
        g[base + d] = gv[j] * rms * nw[d];
    }
}

extern "C" void kernel_launch(void* const* d_in, const int* in_sizes, int n_in,
                              void* d_out, int out_size, void* d_ws, size_t ws_size,
                              hipStream_t stream) {
    const float* a      = (const float*)d_in[0];
    const float* b      = (const float*)d_in[1];
    const float* Wi     = (const float*)d_in[2];
    const float* conv_w = (const float*)d_in[3];
    const float* conv_b = (const float*)d_in[4];
    const float* Wx     = (const float*)d_in[5];
    const float* Wdt    = (const float*)d_in[6];
    const float* bdt    = (const float*)d_in[7];
    const float* A_log  = (const float*)d_in[8];
    const float* Dvec   = (const float*)d_in[9];
    const float* conv_w_b = (const float*)d_in[10];
    const float* conv_b_b = (const float*)d_in[11];
    const float* Wx_b   = (const float*)d_in[12];
    const float* Wdt_b  = (const float*)d_in[13];
    const float* bdt_b  = (const float*)d_in[14];
    const float* A_log_b = (const float*)d_in[15];
    const float* Dvec_b = (const float*)d_in[16];
    const float* Wo     = (const float*)d_in[17];
    const float* nw     = (const float*)d_in[18];
    float* out = (float*)d_out;

    const int M = B_ * L_;              // 2048
    const size_t BLD = (size_t)M * DI;  // 4194304 floats
    float* f = (float*)d_ws;
    float* B1 = f;                      // x_f -> dt_f -> y_f -> g
    float* B2 = f + BLD;                // u_f -> x_b -> dt_b -> y_b
    float* B3 = f + 2 * BLD;            // u_b -> z
    float* dblf = f + 3 * BLD;
    float* dblb = dblf + (size_t)M * 96;
    float* Pbuf = dblb + (size_t)M * 96;                    // NCH*B_*NS*DI = 2M floats
    float* Sbuf = Pbuf + (size_t)NCH * B_ * NS * DI;

    dim3 blk(256);
    const int totBLD = M * DI;
    dim3 scanGrid(DI / 256, B_, NCH);

    // ---- forward branch ----
    gemm_bt<<<dim3(DI / 64, M / 64), blk, 0, stream>>>(
        a, DM, Wi, DM, 0, B1, DI, M, DI, DM, L_, 0);
    conv_silu<<<dim3(totBLD / 256), blk, 0, stream>>>(B1, conv_w, conv_b, B2, totBLD);
    gemm_bt<<<dim3(2, M / 64), blk, 0, stream>>>(
        B2, DI, Wx, DI, 0, dblf, 96, M, 96, DI, L_, 0);
    gemm_bt<<<dim3(DI / 64, M / 64), blk, 0, stream>>>(
        dblf, 96, Wdt, RR, 0, B1, DI, M, DI, RR, L_, 0);
    scan_chunk<<<scanGrid, blk, 0, stream>>>(B2, B1, bdt, dblf, A_log, Pbuf, Sbuf);
    scan_combine<<<dim3(B_ * DI / 256), blk, 0, stream>>>(Pbuf, Sbuf);
    scan_apply<<<scanGrid, blk, 0, stream>>>(B2, B1, bdt, dblf, A_log, Dvec, Pbuf, B1);

    // ---- backward branch ----
    gemm_bt<<<dim3(DI / 64, M / 64), blk, 0, stream>>>(
        b, DM, Wi, DM, 0, B2, DI, M, DI, DM, L_, 1);
    conv_silu<<<dim3(totBLD / 256), blk, 0, stream>>>(B2, conv_w_b, conv_b_b, B3, totBLD);
    gemm_bt<<<dim3(2, M / 64), blk, 0, stream>>>(
        B3, DI, Wx_b, DI, 0, dblb, 96, M, 96, DI, L_, 0);
    gemm_bt<<<dim3(DI / 64, M / 64), blk, 0, stream>>>(
        dblb, 96, Wdt_b, RR, 0, B2, DI, M, DI, RR, L_, 0);
    scan_chunk<<<scanGrid, blk, 0, stream>>>(B3, B2, bdt_b, dblb, A_log_b, Pbuf, Sbuf);
    scan_combine<<<dim3(B_ * DI / 256), blk, 0, stream>>>(Pbuf, Sbuf);
    scan_apply<<<scanGrid, blk, 0, stream>>>(B3, B2, bdt_b, dblb, A_log_b, Dvec_b, Pbuf, B2);

    // ---- combine ----
    gemm_bt<<<dim3(DI / 64, M / 64), blk, 0, stream>>>(
        a, DM, Wi, DM, DI, B3, DI, M, DI, DM, L_, 0);
    combine_rms<<<dim3(M), blk, 0, stream>>>(B1, B2, B3, nw, B1);
    gemm_bt<<<dim3(DM / 64, M / 64), blk, 0, stream>>>(
        B1, DI, Wo, DI, 0, out, DM, M, DM, DI, L_, 0);
}

// Round 6
// 632.782 us; speedup vs baseline: 4.4830x; 1.7647x over previous
//
#include <hip/hip_runtime.h>
#include <hip/hip_bf16.h>
#include <cmath>

#define B_ 2
#define L_ 1024
#define DM 1024
#define DI 2048
#define NS 16
#define RR 64
#define KC 4
#define NCH 32
#define CL (L_ / NCH)   // 32

using frag8 = __attribute__((ext_vector_type(8))) short;   // 8 bf16 (4 VGPRs)
using facc4 = __attribute__((ext_vector_type(4))) float;   // MFMA C/D

__device__ __forceinline__ short f2b(float v) {
    __hip_bfloat16 h = __float2bfloat16(v);
    return *(short*)&h;
}

// fp32 -> bf16 cast; optional per-batch flip along L (rows = b*Lseq + l)
__global__ void cvt_bf16(const float* __restrict__ x, short* __restrict__ y,
                         int rows, int cols, int Lseq, int flip) {
    int idx = blockIdx.x * blockDim.x + threadIdx.x;
    if (idx >= rows * cols) return;
    int r = idx / cols, c = idx % cols;
    int sr = r;
    if (flip) { int bb = r / Lseq, ll = r % Lseq; sr = bb * Lseq + (Lseq - 1 - ll); }
    y[(size_t)r * cols + c] = f2b(x[(size_t)sr * cols + c]);
}

__global__ void zero_buf(float* __restrict__ p, int n) {
    int i = blockIdx.x * blockDim.x + threadIdx.x;
    if (i < n) p[i] = 0.f;
}

// MFMA bf16 GEMM: C[M,N] = A[M,K] * W[N,K]^T, 128x128 tile, BK=32.
// A,W bf16 row-major; C fp32. M,N multiples of 128, K multiple of 32.
// LDS layout: [q=k/8][row] of 16B units -> conflict-free staging + frag reads.
__global__ __launch_bounds__(256) void gemm_mfma(
    const short* __restrict__ A, int lda,
    const short* __restrict__ W, int ldw, int wRowOff,
    float* __restrict__ C, int ldc, int K) {
    __shared__ short As[4096];   // 8 KB: unit (q*128+row), q=0..3, row=0..127
    __shared__ short Ws[4096];
    const int tid = threadIdx.x;
    const int lane = tid & 63, wv = tid >> 6;
    const int m0 = blockIdx.y * 128, n0 = blockIdx.x * 128;
    const int wm = (wv & 1) * 64, wn = (wv >> 1) * 64;
    const int sr = tid >> 2;         // staging row 0..63 (round 0), +64 (round 1)
    const int scb = tid & 3;         // staging k-block (8 bf16 = 16B)
    const short* Ap  = A + (size_t)(m0 + sr) * lda + scb * 8;
    const short* Ap2 = Ap + (size_t)64 * lda;
    const short* Wp  = W + (size_t)(n0 + wRowOff + sr) * ldw + scb * 8;
    const short* Wp2 = Wp + (size_t)64 * ldw;
    const int q = lane >> 4, mr = lane & 15;

    facc4 acc[4][4];
#pragma unroll
    for (int i = 0; i < 4; ++i)
#pragma unroll
        for (int j = 0; j < 4; ++j) acc[i][j] = (facc4){0.f, 0.f, 0.f, 0.f};

    for (int k0 = 0; k0 < K; k0 += 32) {
        uint4 a0 = *(const uint4*)(Ap + k0);
        uint4 a1 = *(const uint4*)(Ap2 + k0);
        uint4 w0 = *(const uint4*)(Wp + k0);
        uint4 w1 = *(const uint4*)(Wp2 + k0);
        __syncthreads();
        *(uint4*)&As[(scb * 128 + sr) * 8]        = a0;
        *(uint4*)&As[(scb * 128 + 64 + sr) * 8]   = a1;
        *(uint4*)&Ws[(scb * 128 + sr) * 8]        = w0;
        *(uint4*)&Ws[(scb * 128 + 64 + sr) * 8]   = w1;
        __syncthreads();
        frag8 af[4], wf[4];
#pragma unroll
        for (int t = 0; t < 4; ++t) {
            af[t] = *(const frag8*)&As[(q * 128 + wm + t * 16 + mr) * 8];
            wf[t] = *(const frag8*)&Ws[(q * 128 + wn + t * 16 + mr) * 8];
        }
#pragma unroll
        for (int i = 0; i < 4; ++i)
#pragma unroll
            for (int j = 0; j < 4; ++j)
                acc[i][j] = __builtin_amdgcn_mfma_f32_16x16x32_bf16(af[i], wf[j], acc[i][j], 0, 0, 0);
    }
    // C/D mapping: col = lane&15 (n), row = q*4 + e (m)
#pragma unroll
    for (int i = 0; i < 4; ++i)
#pragma unroll
        for (int j = 0; j < 4; ++j) {
            int gn = n0 + wn + j * 16 + mr;
#pragma unroll
            for (int e = 0; e < 4; ++e) {
                int gm = m0 + wm + i * 16 + q * 4 + e;
                C[(size_t)gm * ldc + gn] = acc[i][j][e];
            }
        }
}

// fp32 VALU GEMM (small/odd shapes): C[M,N] = A[M,K_total] * W[N,K]^T
// grid.z = split-K chunks (chunk len = K param); z>0 path uses atomicAdd (C pre-zeroed).
__global__ void gemm_bt(const float* __restrict__ A, int lda,
                        const float* __restrict__ W, int ldw, int wRowOff,
                        float* __restrict__ C, int ldc,
                        int M, int N, int K, int Lseq, int flip) {
    __shared__ float As[16][68];
    __shared__ float Ws[16][68];
    const int tid = threadIdx.x;          // 256
    const int m0 = blockIdx.y * 64;
    const int n0 = blockIdx.x * 64;
    const int kOff = blockIdx.z * K;
    const bool atomic = gridDim.z > 1;
    const int tx = tid & 15, ty = tid >> 4;
    const int lr = tid >> 2;
    const int lc = (tid & 3) << 2;

    int arow = m0 + lr;
    int srow = arow;
    if (flip) { int bb = arow / Lseq, ll = arow % Lseq; srow = bb * Lseq + (Lseq - 1 - ll); }
    const float* Aptr = A + (size_t)srow * lda + lc + kOff;
    int wrow = n0 + lr;
    const bool wok = wrow < N;
    const float* Wptr = W + (size_t)(wrow + wRowOff) * ldw + lc + kOff;

    float acc[4][4] = {};

    for (int k0 = 0; k0 < K; k0 += 16) {
        float4 av = *(const float4*)(Aptr + k0);
        float4 wv = make_float4(0.f, 0.f, 0.f, 0.f);
        if (wok) wv = *(const float4*)(Wptr + k0);
        __syncthreads();
        As[lc + 0][lr] = av.x; As[lc + 1][lr] = av.y;
        As[lc + 2][lr] = av.z; As[lc + 3][lr] = av.w;
        Ws[lc + 0][lr] = wv.x; Ws[lc + 1][lr] = wv.y;
        Ws[lc + 2][lr] = wv.z; Ws[lc + 3][lr] = wv.w;
        __syncthreads();
#pragma unroll
        for (int kk = 0; kk < 16; ++kk) {
            float4 a4 = *(const float4*)&As[kk][ty * 4];
            float4 w4 = *(const float4*)&Ws[kk][tx * 4];
            float ar[4] = {a4.x, a4.y, a4.z, a4.w};
            float wr[4] = {w4.x, w4.y, w4.z, w4.w};
#pragma unroll
            for (int i = 0; i < 4; ++i)
#pragma unroll
                for (int j = 0; j < 4; ++j) acc[i][j] += ar[i] * wr[j];
        }
    }
#pragma unroll
    for (int i = 0; i < 4; ++i) {
        int gm = m0 + ty * 4 + i;
        int gn = n0 + tx * 4;
        if (gn < N) {
            if (atomic) {
#pragma unroll
                for (int j = 0; j < 4; ++j)
                    atomicAdd(&C[(size_t)gm * ldc + gn + j], acc[i][j]);
            } else {
                float4 st = make_float4(acc[i][0], acc[i][1], acc[i][2], acc[i][3]);
                *(float4*)&C[(size_t)gm * ldc + gn] = st;
            }
        }
    }
}

// depthwise causal conv (K=4) + bias + SiLU
__global__ void conv_silu(const float* __restrict__ x,
                          const float* __restrict__ w,
                          const float* __restrict__ bias,
                          float* __restrict__ y, int total) {
    int idx = blockIdx.x * blockDim.x + threadIdx.x;
    if (idx >= total) return;
    int d = idx % DI;
    int l = (idx / DI) % L_;
    float acc = bias[d];
#pragma unroll
    for (int k = 0; k < KC; ++k) {
        int ls = l + k - (KC - 1);
        if (ls >= 0) acc += x[idx + (size_t)(ls - l) * DI] * w[d * KC + k];
    }
    float s = 1.f / (1.f + __expf(-acc));
    y[idx] = acc * s;
}

__device__ __forceinline__ float softplus2(float raw, float bd2) {
    float x = raw + bd2;
    return (x > 20.f) ? x : log1pf(__expf(x));
}

// Pass A: per-chunk P = prod(dA), S = local scan from h=0. Softplus folded.
__global__ void scan_chunk(const float* __restrict__ u, const float* __restrict__ dtraw,
                           const float* __restrict__ bdt,
                           const float* __restrict__ dbl,
                           const float* __restrict__ A_log,
                           float* __restrict__ Pbuf, float* __restrict__ Sbuf) {
    int d = blockIdx.x * blockDim.x + threadIdx.x;
    int bb = blockIdx.y, c = blockIdx.z;
    float Av[NS], P[NS], S[NS];
#pragma unroll
    for (int n = 0; n < NS; ++n) {
        Av[n] = -__expf(A_log[d * NS + n]);
        P[n] = 1.f; S[n] = 0.f;
    }
    float bd2 = 2.f * bdt[d];
    const int l0 = c * CL;
    const float* up = u + ((size_t)bb * L_ + l0) * DI + d;
    const float* dp = dtraw + ((size_t)bb * L_ + l0) * DI + d;
    const float* blp = dbl + ((size_t)bb * L_ + l0) * 96 + RR;
    for (int l = 0; l < CL; ++l) {
        float del = softplus2(dp[(size_t)l * DI], bd2);
        float du = del * up[(size_t)l * DI];
        const float* Brow = blp + l * 96;
#pragma unroll
        for (int n = 0; n < NS; ++n) {
            float dA = __expf(del * Av[n]);
            P[n] *= dA;
            S[n] = dA * S[n] + du * Brow[n];
        }
    }
    size_t pb = ((size_t)(bb * NCH + c) * NS) * DI + d;
#pragma unroll
    for (int n = 0; n < NS; ++n) {
        Pbuf[pb + (size_t)n * DI] = P[n];
        Sbuf[pb + (size_t)n * DI] = S[n];
    }
}

// Pass B: compose chunk states sequentially; overwrite Pbuf[c] with h_start[c].
__global__ void scan_combine(float* __restrict__ Pbuf, const float* __restrict__ Sbuf) {
    int idx = blockIdx.x * blockDim.x + threadIdx.x;
    int bb = idx / DI, d = idx % DI;
    float h[NS];
#pragma unroll
    for (int n = 0; n < NS; ++n) h[n] = 0.f;
    for (int c = 0; c < NCH; ++c) {
        size_t pb = ((size_t)(bb * NCH + c) * NS) * DI + d;
#pragma unroll
        for (int n = 0; n < NS; ++n) {
            size_t o = pb + (size_t)n * DI;
            float P = Pbuf[o], S = Sbuf[o];
            Pbuf[o] = h[n];
            h[n] = P * h[n] + S;
        }
    }
}

// Pass C: re-run chunk from h_start, emit y. y may alias dtraw.
__global__ void scan_apply(const float* __restrict__ u, const float* dtraw,
                           const float* __restrict__ bdt,
                           const float* __restrict__ dbl,
                           const float* __restrict__ A_log,
                           const float* __restrict__ Dv,
                           const float* __restrict__ Hbuf,
                           float* y) {
    int d = blockIdx.x * blockDim.x + threadIdx.x;
    int bb = blockIdx.y, c = blockIdx.z;
    float Av[NS], h[NS];
    size_t pb = ((size_t)(bb * NCH + c) * NS) * DI + d;
#pragma unroll
    for (int n = 0; n < NS; ++n) {
        Av[n] = -__expf(A_log[d * NS + n]);
        h[n] = Hbuf[pb + (size_t)n * DI];
    }
    float bd2 = 2.f * bdt[d];
    float Dd = Dv[d];
    const int l0 = c * CL;
    const float* up = u + ((size_t)bb * L_ + l0) * DI + d;
    const float* dp = dtraw + ((size_t)bb * L_ + l0) * DI + d;
    const float* blp = dbl + ((size_t)bb * L_ + l0) * 96 + RR;
    float* yp = y + ((size_t)bb * L_ + l0) * DI + d;
    for (int l = 0; l < CL; ++l) {
        float del = softplus2(dp[(size_t)l * DI], bd2);
        float ul = up[(size_t)l * DI];
        float du = del * ul;
        const float* Brow = blp + l * 96;
        float acc = 0.f;
#pragma unroll
        for (int n = 0; n < NS; ++n) {
            float dA = __expf(del * Av[n]);
            h[n] = dA * h[n] + du * Brow[n];
            acc += h[n] * Brow[NS + n];
        }
        yp[(size_t)l * DI] = acc + ul * Dd;
    }
}

// g = (y_f + flip(y_b)) * silu(z); rmsnorm; emit bf16 for the final MFMA GEMM.
__global__ void combine_rms(const float* __restrict__ yf, const float* __restrict__ yb,
                            const float* __restrict__ z,
                            const float* __restrict__ nw,
                            short* __restrict__ g) {
    int row = blockIdx.x;
    int bb = row / L_, l = row % L_;
    int tid = threadIdx.x;
    size_t base = (size_t)row * DI;
    size_t baseb = ((size_t)bb * L_ + (L_ - 1 - l)) * DI;
    float gv[8];
    float ss = 0.f;
#pragma unroll
    for (int j = 0; j < 8; ++j) {
        int d = tid + j * 256;
        float yy = yf[base + d] + yb[baseb + d];
        float zz = z[base + d];
        float s = zz / (1.f + __expf(-zz));
        float gg = yy * s;
        gv[j] = gg;
        ss += gg * gg;
    }
#pragma unroll
    for (int off = 32; off > 0; off >>= 1) ss += __shfl_down(ss, off, 64);
    __shared__ float red[4];
    if ((tid & 63) == 0) red[tid >> 6] = ss;
    __syncthreads();
    float tot = red[0] + red[1] + red[2] + red[3];
    float rms = rsqrtf(tot / (float)DI + 1e-5f);
#pragma unroll
    for (int j = 0; j < 8; ++j) {
        int d = tid + j * 256;
        g[base + d] = f2b(gv[j] * rms * nw[d]);
    }
}

extern "C" void kernel_launch(void* const* d_in, const int* in_sizes, int n_in,
                              void* d_out, int out_size, void* d_ws, size_t ws_size,
                              hipStream_t stream) {
    const float* a      = (const float*)d_in[0];
    const float* b      = (const float*)d_in[1];
    const float* Wi     = (const float*)d_in[2];
    const float* conv_w = (const float*)d_in[3];
    const float* conv_b = (const float*)d_in[4];
    const float* Wx     = (const float*)d_in[5];
    const float* Wdt    = (const float*)d_in[6];
    const float* bdt    = (const float*)d_in[7];
    const float* A_log  = (const float*)d_in[8];
    const float* Dvec   = (const float*)d_in[9];
    const float* conv_w_b = (const float*)d_in[10];
    const float* conv_b_b = (const float*)d_in[11];
    const float* Wx_b   = (const float*)d_in[12];
    const float* Wdt_b  = (const float*)d_in[13];
    const float* bdt_b  = (const float*)d_in[14];
    const float* A_log_b = (const float*)d_in[15];
    const float* Dvec_b = (const float*)d_in[16];
    const float* Wo     = (const float*)d_in[17];
    const float* nw     = (const float*)d_in[18];
    float* out = (float*)d_out;

    const int M = B_ * L_;              // 2048
    const size_t BLD = (size_t)M * DI;  // 4194304
    float* f = (float*)d_ws;
    float* B1 = f;                      // x_f -> dt_f -> y_f
    float* B2 = f + BLD;                // u_f -> x_b -> dt_b -> y_b
    float* B3 = f + 2 * BLD;            // u_b -> z
    float* dblf = f + 3 * BLD;
    float* dblb = dblf + (size_t)M * 96;
    float* Pbuf = dblb + (size_t)M * 96;
    float* Sbuf = Pbuf + (size_t)NCH * B_ * NS * DI;   // 2M each
    short* abf  = (short*)(Sbuf + (size_t)NCH * B_ * NS * DI);  // 2M shorts
    short* Wibf = abf + (size_t)2 * DI * DM;                    // 4M shorts
    short* gbf  = Wibf + (size_t)2 * DI * DM;                   // 4M shorts
    short* bbf  = gbf;                  // 2M shorts; dead before gbf written
    short* Wobf = (short*)Pbuf;         // 2M shorts; converted after scans done

    dim3 blk(256);
    const int totBLD = M * DI;
    dim3 scanGrid(DI / 256, B_, NCH);
    const int ndbl = M * 96;

    // ---- input casts ----
    cvt_bf16<<<dim3(M * DM / 256), blk, 0, stream>>>(a, abf, M, DM, L_, 0);
    cvt_bf16<<<dim3(M * DM / 256), blk, 0, stream>>>(b, bbf, M, DM, L_, 1);
    cvt_bf16<<<dim3(2 * DI * DM / 256), blk, 0, stream>>>(Wi, Wibf, 2 * DI, DM, L_, 0);

    // ---- forward branch ----
    gemm_mfma<<<dim3(DI / 128, M / 128), blk, 0, stream>>>(abf, DM, Wibf, DM, 0, B1, DI, DM);
    conv_silu<<<dim3(totBLD / 256), blk, 0, stream>>>(B1, conv_w, conv_b, B2, totBLD);
    zero_buf<<<dim3(ndbl / 256), blk, 0, stream>>>(dblf, ndbl);
    gemm_bt<<<dim3(2, M / 64, 8), blk, 0, stream>>>(
        B2, DI, Wx, DI, 0, dblf, 96, M, 96, DI / 8, L_, 0);
    gemm_bt<<<dim3(DI / 64, M / 64), blk, 0, stream>>>(
        dblf, 96, Wdt, RR, 0, B1, DI, M, DI, RR, L_, 0);
    scan_chunk<<<scanGrid, blk, 0, stream>>>(B2, B1, bdt, dblf, A_log, Pbuf, Sbuf);
    scan_combine<<<dim3(B_ * DI / 256), blk, 0, stream>>>(Pbuf, Sbuf);
    scan_apply<<<scanGrid, blk, 0, stream>>>(B2, B1, bdt, dblf, A_log, Dvec, Pbuf, B1);

    // ---- backward branch ----
    gemm_mfma<<<dim3(DI / 128, M / 128), blk, 0, stream>>>(bbf, DM, Wibf, DM, 0, B2, DI, DM);
    conv_silu<<<dim3(totBLD / 256), blk, 0, stream>>>(B2, conv_w_b, conv_b_b, B3, totBLD);
    zero_buf<<<dim3(ndbl / 256), blk, 0, stream>>>(dblb, ndbl);
    gemm_bt<<<dim3(2, M / 64, 8), blk, 0, stream>>>(
        B3, DI, Wx_b, DI, 0, dblb, 96, M, 96, DI / 8, L_, 0);
    gemm_bt<<<dim3(DI / 64, M / 64), blk, 0, stream>>>(
        dblb, 96, Wdt_b, RR, 0, B2, DI, M, DI, RR, L_, 0);
    scan_chunk<<<scanGrid, blk, 0, stream>>>(B3, B2, bdt_b, dblb, A_log_b, Pbuf, Sbuf);
    scan_combine<<<dim3(B_ * DI / 256), blk, 0, stream>>>(Pbuf, Sbuf);
    scan_apply<<<scanGrid, blk, 0, stream>>>(B3, B2, bdt_b, dblb, A_log_b, Dvec_b, Pbuf, B2);

    // ---- combine ----
    // z = a @ Wi[DI:2*DI].T -> B3
    gemm_mfma<<<dim3(DI / 128, M / 128), blk, 0, stream>>>(abf, DM, Wibf, DM, DI, B3, DI, DM);
    combine_rms<<<dim3(M), blk, 0, stream>>>(B1, B2, B3, nw, gbf);
    // Wo cast (Pbuf region is free now), then out = g @ Wo.T
    cvt_bf16<<<dim3(DM * DI / 256), blk, 0, stream>>>(Wo, Wobf, DM, DI, L_, 0);
    gemm_mfma<<<dim3(DM / 128, M / 128), blk, 0, stream>>>(gbf, DI, Wobf, DI, 0, out, DM, DI);
}

// Round 7
// 594.760 us; speedup vs baseline: 4.7696x; 1.0639x over previous
//
#include <hip/hip_runtime.h>
#include <hip/hip_bf16.h>
#include <cmath>

#define B_ 2
#define L_ 1024
#define DM 1024
#define DI 2048
#define NS 16
#define RR 64
#define KC 4
#define NCH 32
#define CL (L_ / NCH)   // 32

using frag8 = __attribute__((ext_vector_type(8))) short;   // 8 bf16 (4 VGPRs)
using facc4 = __attribute__((ext_vector_type(4))) float;   // MFMA C/D

__device__ __forceinline__ short f2b(float v) {
    __hip_bfloat16 h = __float2bfloat16(v);
    return *(short*)&h;
}

// async global->LDS DMA, 16 B per lane. LDS dest is wave-uniform base + lane*16.
__device__ __forceinline__ void async_ld16(const void* g, void* l) {
    __builtin_amdgcn_global_load_lds(
        (const __attribute__((address_space(1))) unsigned int*)g,
        (__attribute__((address_space(3))) unsigned int*)l, 16, 0, 0);
}

// fp32 -> bf16 cast; optional per-batch flip along L (rows = b*Lseq + l)
__global__ void cvt_bf16(const float* __restrict__ x, short* __restrict__ y,
                         int rows, int cols, int Lseq, int flip) {
    int idx = blockIdx.x * blockDim.x + threadIdx.x;
    if (idx >= rows * cols) return;
    int r = idx / cols, c = idx % cols;
    int sr = r;
    if (flip) { int bb = r / Lseq, ll = r % Lseq; sr = bb * Lseq + (Lseq - 1 - ll); }
    y[(size_t)r * cols + c] = f2b(x[(size_t)sr * cols + c]);
}

__global__ void zero_buf(float* __restrict__ p, int n) {
    int i = blockIdx.x * blockDim.x + threadIdx.x;
    if (i < n) p[i] = 0.f;
}

// MFMA bf16 GEMM: C[M,N] = A[M,K] * W[N,K]^T, tile BM x 64, BK=32.
// A,W bf16 row-major; C fp32. M mult of BM, N mult of 64, K mult of 32.
// LDS layout: unit(row,q) = row*4+q (16B units) == lane order of global_load_lds.
template <int BM>
__global__ __launch_bounds__(256) void gemm_mfma(
    const short* __restrict__ A, int lda,
    const short* __restrict__ W, int ldw, int wRowOff,
    float* __restrict__ C, int ldc, int K) {
    constexpr int MF = BM / 32;                 // m-frags per wave (2 or 4)
    __shared__ __align__(16) short As[BM * 32];
    __shared__ __align__(16) short Ws[64 * 32];
    const int tid = threadIdx.x;
    const int lane = tid & 63, wv = tid >> 6;
    const int m0 = blockIdx.y * BM, n0 = blockIdx.x * 64;
    const int wm = (wv & 1) * (BM / 2), wn = (wv >> 1) * 32;
    const int q = lane >> 4, mr = lane & 15;
    const int srow = lane >> 2, skb = lane & 3;   // staging: 4 lanes/row, 16 rows/inst

    const short* Ag = A + (size_t)(m0 + wv * 16 + srow) * lda + skb * 8;
    const short* Wg = W + (size_t)(n0 + wRowOff + wv * 16 + srow) * ldw + skb * 8;
    short* lA = &As[wv * 512];
    short* lW = &Ws[wv * 512];

    facc4 acc[MF][2];
#pragma unroll
    for (int i = 0; i < MF; ++i)
#pragma unroll
        for (int j = 0; j < 2; ++j) acc[i][j] = (facc4){0.f, 0.f, 0.f, 0.f};

    for (int k0 = 0; k0 < K; k0 += 32) {
        __syncthreads();                       // prev iter done reading LDS
        async_ld16(Ag + k0, lA);
        if constexpr (BM == 128) {
            async_ld16(Ag + (size_t)64 * lda + k0, &As[wv * 512 + 2048]);
        }
        async_ld16(Wg + k0, lW);
        __syncthreads();                       // drains vmcnt -> data in LDS
        frag8 af[MF], wf[2];
#pragma unroll
        for (int t = 0; t < MF; ++t)
            af[t] = *(const frag8*)&As[((wm + t * 16 + mr) * 4 + q) * 8];
#pragma unroll
        for (int j = 0; j < 2; ++j)
            wf[j] = *(const frag8*)&Ws[((wn + j * 16 + mr) * 4 + q) * 8];
#pragma unroll
        for (int i = 0; i < MF; ++i)
#pragma unroll
            for (int j = 0; j < 2; ++j)
                acc[i][j] = __builtin_amdgcn_mfma_f32_16x16x32_bf16(af[i], wf[j], acc[i][j], 0, 0, 0);
    }
    // C/D mapping: col = lane&15, row = q*4 + e
#pragma unroll
    for (int i = 0; i < MF; ++i)
#pragma unroll
        for (int j = 0; j < 2; ++j) {
            int gn = n0 + wn + j * 16 + mr;
#pragma unroll
            for (int e = 0; e < 4; ++e) {
                int gm = m0 + wm + i * 16 + q * 4 + e;
                C[(size_t)gm * ldc + gn] = acc[i][j][e];
            }
        }
}

// fp32 VALU GEMM (small/odd shapes): C[M,N] = A[M,K_total] * W[N,K]^T
// grid.z = split-K chunks (chunk len = K); z>0 uses atomicAdd (C pre-zeroed).
__global__ void gemm_bt(const float* __restrict__ A, int lda,
                        const float* __restrict__ W, int ldw, int wRowOff,
                        float* __restrict__ C, int ldc,
                        int M, int N, int K, int Lseq, int flip) {
    __shared__ float As[16][68];
    __shared__ float Ws[16][68];
    const int tid = threadIdx.x;          // 256
    const int m0 = blockIdx.y * 64;
    const int n0 = blockIdx.x * 64;
    const int kOff = blockIdx.z * K;
    const bool atomic = gridDim.z > 1;
    const int tx = tid & 15, ty = tid >> 4;
    const int lr = tid >> 2;
    const int lc = (tid & 3) << 2;

    int arow = m0 + lr;
    int srow = arow;
    if (flip) { int bb = arow / Lseq, ll = arow % Lseq; srow = bb * Lseq + (Lseq - 1 - ll); }
    const float* Aptr = A + (size_t)srow * lda + lc + kOff;
    int wrow = n0 + lr;
    const bool wok = wrow < N;
    const float* Wptr = W + (size_t)(wrow + wRowOff) * ldw + lc + kOff;

    float acc[4][4] = {};

    for (int k0 = 0; k0 < K; k0 += 16) {
        float4 av = *(const float4*)(Aptr + k0);
        float4 wv = make_float4(0.f, 0.f, 0.f, 0.f);
        if (wok) wv = *(const float4*)(Wptr + k0);
        __syncthreads();
        As[lc + 0][lr] = av.x; As[lc + 1][lr] = av.y;
        As[lc + 2][lr] = av.z; As[lc + 3][lr] = av.w;
        Ws[lc + 0][lr] = wv.x; Ws[lc + 1][lr] = wv.y;
        Ws[lc + 2][lr] = wv.z; Ws[lc + 3][lr] = wv.w;
        __syncthreads();
#pragma unroll
        for (int kk = 0; kk < 16; ++kk) {
            float4 a4 = *(const float4*)&As[kk][ty * 4];
            float4 w4 = *(const float4*)&Ws[kk][tx * 4];
            float ar[4] = {a4.x, a4.y, a4.z, a4.w};
            float wr[4] = {w4.x, w4.y, w4.z, w4.w};
#pragma unroll
            for (int i = 0; i < 4; ++i)
#pragma unroll
                for (int j = 0; j < 4; ++j) acc[i][j] += ar[i] * wr[j];
        }
    }
#pragma unroll
    for (int i = 0; i < 4; ++i) {
        int gm = m0 + ty * 4 + i;
        int gn = n0 + tx * 4;
        if (gn < N) {
            if (atomic) {
#pragma unroll
                for (int j = 0; j < 4; ++j)
                    atomicAdd(&C[(size_t)gm * ldc + gn + j], acc[i][j]);
            } else {
                float4 st = make_float4(acc[i][0], acc[i][1], acc[i][2], acc[i][3]);
                *(float4*)&C[(size_t)gm * ldc + gn] = st;
            }
        }
    }
}

// depthwise causal conv (K=4) + bias + SiLU
__global__ void conv_silu(const float* __restrict__ x,
                          const float* __restrict__ w,
                          const float* __restrict__ bias,
                          float* __restrict__ y, int total) {
    int idx = blockIdx.x * blockDim.x + threadIdx.x;
    if (idx >= total) return;
    int d = idx % DI;
    int l = (idx / DI) % L_;
    float acc = bias[d];
#pragma unroll
    for (int k = 0; k < KC; ++k) {
        int ls = l + k - (KC - 1);
        if (ls >= 0) acc += x[idx + (size_t)(ls - l) * DI] * w[d * KC + k];
    }
    float s = 1.f / (1.f + __expf(-acc));
    y[idx] = acc * s;
}

__device__ __forceinline__ float softplus2(float raw, float bd2) {
    float x = raw + bd2;
    return (x > 20.f) ? x : log1pf(__expf(x));
}

// Pass A: per-chunk P = prod(dA), S = local scan from h=0. Softplus folded.
__global__ void scan_chunk(const float* __restrict__ u, const float* __restrict__ dtraw,
                           const float* __restrict__ bdt,
                           const float* __restrict__ dbl,
                           const float* __restrict__ A_log,
                           float* __restrict__ Pbuf, float* __restrict__ Sbuf) {
    int d = blockIdx.x * blockDim.x + threadIdx.x;
    int bb = blockIdx.y, c = blockIdx.z;
    float Av[NS], P[NS], S[NS];
#pragma unroll
    for (int n = 0; n < NS; ++n) {
        Av[n] = -__expf(A_log[d * NS + n]);
        P[n] = 1.f; S[n] = 0.f;
    }
    float bd2 = 2.f * bdt[d];
    const int l0 = c * CL;
    const float* up = u + ((size_t)bb * L_ + l0) * DI + d;
    const float* dp = dtraw + ((size_t)bb * L_ + l0) * DI + d;
    const float* blp = dbl + ((size_t)bb * L_ + l0) * 96 + RR;
    for (int l = 0; l < CL; ++l) {
        float del = softplus2(dp[(size_t)l * DI], bd2);
        float du = del * up[(size_t)l * DI];
        const float* Brow = blp + l * 96;
#pragma unroll
        for (int n = 0; n < NS; ++n) {
            float dA = __expf(del * Av[n]);
            P[n] *= dA;
            S[n] = dA * S[n] + du * Brow[n];
        }
    }
    size_t pb = ((size_t)(bb * NCH + c) * NS) * DI + d;
#pragma unroll
    for (int n = 0; n < NS; ++n) {
        Pbuf[pb + (size_t)n * DI] = P[n];
        Sbuf[pb + (size_t)n * DI] = S[n];
    }
}

// Pass B: compose chunk states sequentially; overwrite Pbuf[c] with h_start[c].
__global__ void scan_combine(float* __restrict__ Pbuf, const float* __restrict__ Sbuf) {
    int idx = blockIdx.x * blockDim.x + threadIdx.x;
    int bb = idx / DI, d = idx % DI;
    float h[NS];
#pragma unroll
    for (int n = 0; n < NS; ++n) h[n] = 0.f;
    for (int c = 0; c < NCH; ++c) {
        size_t pb = ((size_t)(bb * NCH + c) * NS) * DI + d;
#pragma unroll
        for (int n = 0; n < NS; ++n) {
            size_t o = pb + (size_t)n * DI;
            float P = Pbuf[o], S = Sbuf[o];
            Pbuf[o] = h[n];
            h[n] = P * h[n] + S;
        }
    }
}

// Pass C: re-run chunk from h_start, emit y. y may alias dtraw.
__global__ void scan_apply(const float* __restrict__ u, const float* dtraw,
                           const float* __restrict__ bdt,
                           const float* __restrict__ dbl,
                           const float* __restrict__ A_log,
                           const float* __restrict__ Dv,
                           const float* __restrict__ Hbuf,
                           float* y) {
    int d = blockIdx.x * blockDim.x + threadIdx.x;
    int bb = blockIdx.y, c = blockIdx.z;
    float Av[NS], h[NS];
    size_t pb = ((size_t)(bb * NCH + c) * NS) * DI + d;
#pragma unroll
    for (int n = 0; n < NS; ++n) {
        Av[n] = -__expf(A_log[d * NS + n]);
        h[n] = Hbuf[pb + (size_t)n * DI];
    }
    float bd2 = 2.f * bdt[d];
    float Dd = Dv[d];
    const int l0 = c * CL;
    const float* up = u + ((size_t)bb * L_ + l0) * DI + d;
    const float* dp = dtraw + ((size_t)bb * L_ + l0) * DI + d;
    const float* blp = dbl + ((size_t)bb * L_ + l0) * 96 + RR;
    float* yp = y + ((size_t)bb * L_ + l0) * DI + d;
    for (int l = 0; l < CL; ++l) {
        float del = softplus2(dp[(size_t)l * DI], bd2);
        float ul = up[(size_t)l * DI];
        float du = del * ul;
        const float* Brow = blp + l * 96;
        float acc = 0.f;
#pragma unroll
        for (int n = 0; n < NS; ++n) {
            float dA = __expf(del * Av[n]);
            h[n] = dA * h[n] + du * Brow[n];
            acc += h[n] * Brow[NS + n];
        }
        yp[(size_t)l * DI] = acc + ul * Dd;
    }
}

// g = (y_f + flip(y_b)) * silu(z); rmsnorm; emit bf16 for the final MFMA GEMM.
__global__ void combine_rms(const float* __restrict__ yf, const float* __restrict__ yb,
                            const float* __restrict__ z,
                            const float* __restrict__ nw,
                            short* __restrict__ g) {
    int row = blockIdx.x;
    int bb = row / L_, l = row % L_;
    int tid = threadIdx.x;
    size_t base = (size_t)row * DI;
    size_t baseb = ((size_t)bb * L_ + (L_ - 1 - l)) * DI;
    float gv[8];
    float ss = 0.f;
#pragma unroll
    for (int j = 0; j < 8; ++j) {
        int d = tid + j * 256;
        float yy = yf[base + d] + yb[baseb + d];
        float zz = z[base + d];
        float s = zz / (1.f + __expf(-zz));
        float gg = yy * s;
        gv[j] = gg;
        ss += gg * gg;
    }
#pragma unroll
    for (int off = 32; off > 0; off >>= 1) ss += __shfl_down(ss, off, 64);
    __shared__ float red[4];
    if ((tid & 63) == 0) red[tid >> 6] = ss;
    __syncthreads();
    float tot = red[0] + red[1] + red[2] + red[3];
    float rms = rsqrtf(tot / (float)DI + 1e-5f);
#pragma unroll
    for (int j = 0; j < 8; ++j) {
        int d = tid + j * 256;
        g[base + d] = f2b(gv[j] * rms * nw[d]);
    }
}

extern "C" void kernel_launch(void* const* d_in, const int* in_sizes, int n_in,
                              void* d_out, int out_size, void* d_ws, size_t ws_size,
                              hipStream_t stream) {
    const float* a      = (const float*)d_in[0];
    const float* b      = (const float*)d_in[1];
    const float* Wi     = (const float*)d_in[2];
    const float* conv_w = (const float*)d_in[3];
    const float* conv_b = (const float*)d_in[4];
    const float* Wx     = (const float*)d_in[5];
    const float* Wdt    = (const float*)d_in[6];
    const float* bdt    = (const float*)d_in[7];
    const float* A_log  = (const float*)d_in[8];
    const float* Dvec   = (const float*)d_in[9];
    const float* conv_w_b = (const float*)d_in[10];
    const float* conv_b_b = (const float*)d_in[11];
    const float* Wx_b   = (const float*)d_in[12];
    const float* Wdt_b  = (const float*)d_in[13];
    const float* bdt_b  = (const float*)d_in[14];
    const float* A_log_b = (const float*)d_in[15];
    const float* Dvec_b = (const float*)d_in[16];
    const float* Wo     = (const float*)d_in[17];
    const float* nw     = (const float*)d_in[18];
    float* out = (float*)d_out;

    const int M = B_ * L_;              // 2048
    const size_t BLD = (size_t)M * DI;  // 4194304
    float* f = (float*)d_ws;
    float* B1 = f;                      // x_f -> dt_f -> y_f
    float* B2 = f + BLD;                // u_f -> x_b -> dt_b -> y_b
    float* B3 = f + 2 * BLD;            // u_b -> z
    float* dblf = f + 3 * BLD;
    float* dblb = dblf + (size_t)M * 96;
    float* Pbuf = dblb + (size_t)M * 96;
    float* Sbuf = Pbuf + (size_t)NCH * B_ * NS * DI;   // 2M each
    short* abf  = (short*)(Sbuf + (size_t)NCH * B_ * NS * DI);  // 2M shorts
    short* Wibf = abf + (size_t)2 * DI * DM;                    // 4M shorts
    short* gbf  = Wibf + (size_t)2 * DI * DM;                   // 4M shorts
    short* bbf  = gbf;                  // 2M shorts; dead before gbf written
    short* Wobf = (short*)Pbuf;         // 2M shorts; converted after scans done

    dim3 blk(256);
    const int totBLD = M * DI;
    dim3 scanGrid(DI / 256, B_, NCH);
    const int ndbl = M * 96;

    // ---- input casts ----
    cvt_bf16<<<dim3(M * DM / 256), blk, 0, stream>>>(a, abf, M, DM, L_, 0);
    cvt_bf16<<<dim3(M * DM / 256), blk, 0, stream>>>(b, bbf, M, DM, L_, 1);
    cvt_bf16<<<dim3(2 * DI * DM / 256), blk, 0, stream>>>(Wi, Wibf, 2 * DI, DM, L_, 0);

    // ---- forward branch ----
    gemm_mfma<128><<<dim3(DI / 64, M / 128), blk, 0, stream>>>(abf, DM, Wibf, DM, 0, B1, DI, DM);
    conv_silu<<<dim3(totBLD / 256), blk, 0, stream>>>(B1, conv_w, conv_b, B2, totBLD);
    zero_buf<<<dim3(ndbl / 256), blk, 0, stream>>>(dblf, ndbl);
    gemm_bt<<<dim3(2, M / 64, 8), blk, 0, stream>>>(
        B2, DI, Wx, DI, 0, dblf, 96, M, 96, DI / 8, L_, 0);
    gemm_bt<<<dim3(DI / 64, M / 64), blk, 0, stream>>>(
        dblf, 96, Wdt, RR, 0, B1, DI, M, DI, RR, L_, 0);
    scan_chunk<<<scanGrid, blk, 0, stream>>>(B2, B1, bdt, dblf, A_log, Pbuf, Sbuf);
    scan_combine<<<dim3(B_ * DI / 256), blk, 0, stream>>>(Pbuf, Sbuf);
    scan_apply<<<scanGrid, blk, 0, stream>>>(B2, B1, bdt, dblf, A_log, Dvec, Pbuf, B1);

    // ---- backward branch ----
    gemm_mfma<128><<<dim3(DI / 64, M / 128), blk, 0, stream>>>(bbf, DM, Wibf, DM, 0, B2, DI, DM);
    conv_silu<<<dim3(totBLD / 256), blk, 0, stream>>>(B2, conv_w_b, conv_b_b, B3, totBLD);
    zero_buf<<<dim3(ndbl / 256), blk, 0, stream>>>(dblb, ndbl);
    gemm_bt<<<dim3(2, M / 64, 8), blk, 0, stream>>>(
        B3, DI, Wx_b, DI, 0, dblb, 96, M, 96, DI / 8, L_, 0);
    gemm_bt<<<dim3(DI / 64, M / 64), blk, 0, stream>>>(
        dblb, 96, Wdt_b, RR, 0, B2, DI, M, DI, RR, L_, 0);
    scan_chunk<<<scanGrid, blk, 0, stream>>>(B3, B2, bdt_b, dblb, A_log_b, Pbuf, Sbuf);
    scan_combine<<<dim3(B_ * DI / 256), blk, 0, stream>>>(Pbuf, Sbuf);
    scan_apply<<<scanGrid, blk, 0, stream>>>(B3, B2, bdt_b, dblb, A_log_b, Dvec_b, Pbuf, B2);

    // ---- combine ----
    // z = a @ Wi[DI:2*DI].T -> B3
    gemm_mfma<128><<<dim3(DI / 64, M / 128), blk, 0, stream>>>(abf, DM, Wibf, DM, DI, B3, DI, DM);
    combine_rms<<<dim3(M), blk, 0, stream>>>(B1, B2, B3, nw, gbf);
    // Wo cast (Pbuf region free now), then out = g @ Wo.T
    cvt_bf16<<<dim3(DM * DI / 256), blk, 0, stream>>>(Wo, Wobf, DM, DI, L_, 0);
    gemm_mfma<64><<<dim3(DM / 64, M / 64), blk, 0, stream>>>(gbf, DI, Wobf, DI, 0, out, DM, DI);
}

// Round 8
// 490.206 us; speedup vs baseline: 5.7869x; 1.2133x over previous
//
#include <hip/hip_runtime.h>
#include <hip/hip_bf16.h>
#include <cmath>

#define B_ 2
#define L_ 1024
#define DM 1024
#define DI 2048
#define NS 16
#define RR 64
#define KC 4
#define NCH 32
#define CL (L_ / NCH)   // 32
#define NSPLIT 16       // dbl GEMM split-K factor

using frag8 = __attribute__((ext_vector_type(8))) short;   // 8 bf16 (4 VGPRs)
using facc4 = __attribute__((ext_vector_type(4))) float;   // MFMA C/D

__device__ __forceinline__ short f2b(float v) {
    __hip_bfloat16 h = __float2bfloat16(v);
    return *(short*)&h;
}

// async global->LDS DMA, 16 B per lane. LDS dest is wave-uniform base + lane*16.
__device__ __forceinline__ void async_ld16(const void* g, void* l) {
    __builtin_amdgcn_global_load_lds(
        (const __attribute__((address_space(1))) unsigned int*)g,
        (__attribute__((address_space(3))) unsigned int*)l, 16, 0, 0);
}

// fp32 -> bf16 cast; optional per-batch flip along L (rows = b*Lseq + l)
__global__ void cvt_bf16(const float* __restrict__ x, short* __restrict__ y,
                         int rows, int cols, int Lseq, int flip) {
    int idx = blockIdx.x * blockDim.x + threadIdx.x;
    if (idx >= rows * cols) return;
    int r = idx / cols, c = idx % cols;
    int sr = r;
    if (flip) { int bb = r / Lseq, ll = r % Lseq; sr = bb * Lseq + (Lseq - 1 - ll); }
    y[(size_t)r * cols + c] = f2b(x[(size_t)sr * cols + c]);
}

// one launch converting all the small weights
__global__ void cvt_weights(const float* __restrict__ Wx, const float* __restrict__ Wxb,
                            const float* __restrict__ Wdt, const float* __restrict__ Wdtb,
                            const float* __restrict__ Wo,
                            short* __restrict__ oWx, short* __restrict__ oWxb,
                            short* __restrict__ oWdt, short* __restrict__ oWdtb,
                            short* __restrict__ oWo) {
    int i = blockIdx.x * blockDim.x + threadIdx.x;
    const int S0 = 96 * DI, S2 = DI * RR, S4 = DM * DI;
    if (i < S0) { oWx[i] = f2b(Wx[i]); return; } i -= S0;
    if (i < S0) { oWxb[i] = f2b(Wxb[i]); return; } i -= S0;
    if (i < S2) { oWdt[i] = f2b(Wdt[i]); return; } i -= S2;
    if (i < S2) { oWdtb[i] = f2b(Wdtb[i]); return; } i -= S2;
    if (i < S4) { oWo[i] = f2b(Wo[i]); }
}

// MFMA bf16 GEMM: C[M,N] = A[M,K] * W[N,K]^T, tile BM x 64, BK=32.
// LDS layout: unit(row,q) = row*4+q (16B units) == lane order of global_load_lds.
template <int BM>
__global__ __launch_bounds__(256) void gemm_mfma(
    const short* __restrict__ A, int lda,
    const short* __restrict__ W, int ldw, int wRowOff,
    float* __restrict__ C, int ldc, int K) {
    constexpr int MF = BM / 32;
    __shared__ __align__(16) short As[BM * 32];
    __shared__ __align__(16) short Ws[64 * 32];
    const int tid = threadIdx.x;
    const int lane = tid & 63, wv = tid >> 6;
    const int m0 = blockIdx.y * BM, n0 = blockIdx.x * 64;
    const int wm = (wv & 1) * (BM / 2), wn = (wv >> 1) * 32;
    const int q = lane >> 4, mr = lane & 15;
    const int srow = lane >> 2, skb = lane & 3;

    const short* Ag = A + (size_t)(m0 + wv * 16 + srow) * lda + skb * 8;
    const short* Wg = W + (size_t)(n0 + wRowOff + wv * 16 + srow) * ldw + skb * 8;
    short* lA = &As[wv * 512];
    short* lW = &Ws[wv * 512];

    facc4 acc[MF][2];
#pragma unroll
    for (int i = 0; i < MF; ++i)
#pragma unroll
        for (int j = 0; j < 2; ++j) acc[i][j] = (facc4){0.f, 0.f, 0.f, 0.f};

    for (int k0 = 0; k0 < K; k0 += 32) {
        __syncthreads();
        async_ld16(Ag + k0, lA);
        if constexpr (BM == 128) {
            async_ld16(Ag + (size_t)64 * lda + k0, &As[wv * 512 + 2048]);
        }
        async_ld16(Wg + k0, lW);
        __syncthreads();
        frag8 af[MF], wf[2];
#pragma unroll
        for (int t = 0; t < MF; ++t)
            af[t] = *(const frag8*)&As[((wm + t * 16 + mr) * 4 + q) * 8];
#pragma unroll
        for (int j = 0; j < 2; ++j)
            wf[j] = *(const frag8*)&Ws[((wn + j * 16 + mr) * 4 + q) * 8];
#pragma unroll
        for (int i = 0; i < MF; ++i)
#pragma unroll
            for (int j = 0; j < 2; ++j)
                acc[i][j] = __builtin_amdgcn_mfma_f32_16x16x32_bf16(af[i], wf[j], acc[i][j], 0, 0, 0);
    }
#pragma unroll
    for (int i = 0; i < MF; ++i)
#pragma unroll
        for (int j = 0; j < 2; ++j) {
            int gn = n0 + wn + j * 16 + mr;
#pragma unroll
            for (int e = 0; e < 4; ++e) {
                int gm = m0 + wm + i * 16 + q * 4 + e;
                C[(size_t)gm * ldc + gn] = acc[i][j][e];
            }
        }
}

// dbl GEMM: part[z][M][96] = A[M, kchunk] * W[96, kchunk]^T  (tile 128x96, split-K)
__global__ __launch_bounds__(256) void gemm_mfma_dbl(
    const short* __restrict__ A, int lda,
    const short* __restrict__ W, int ldw,
    float* __restrict__ part, int Kchunk) {
    __shared__ __align__(16) short As[128 * 32];
    __shared__ __align__(16) short Ws[96 * 32];
    const int tid = threadIdx.x;
    const int lane = tid & 63, wv = tid >> 6;
    const int m0 = blockIdx.y * 128;
    const int kOff = blockIdx.z * Kchunk;
    const int wm = (wv & 1) * 64, wn = (wv >> 1) * 48;
    const int q = lane >> 4, mr = lane & 15;
    const int srow = lane >> 2, skb = lane & 3;

    const short* Ag = A + (size_t)(m0 + wv * 16 + srow) * lda + skb * 8 + kOff;
    const short* Wg = W + (size_t)(wv * 16 + srow) * ldw + skb * 8 + kOff;

    facc4 acc[4][3];
#pragma unroll
    for (int i = 0; i < 4; ++i)
#pragma unroll
        for (int j = 0; j < 3; ++j) acc[i][j] = (facc4){0.f, 0.f, 0.f, 0.f};

    for (int k0 = 0; k0 < Kchunk; k0 += 32) {
        __syncthreads();
        async_ld16(Ag + k0, &As[wv * 512]);
        async_ld16(Ag + (size_t)64 * lda + k0, &As[wv * 512 + 2048]);
        async_ld16(Wg + k0, &Ws[wv * 512]);
        if (wv < 2) async_ld16(Wg + (size_t)64 * ldw + k0, &Ws[wv * 512 + 2048]);
        __syncthreads();
        frag8 af[4], wf[3];
#pragma unroll
        for (int t = 0; t < 4; ++t)
            af[t] = *(const frag8*)&As[((wm + t * 16 + mr) * 4 + q) * 8];
#pragma unroll
        for (int j = 0; j < 3; ++j)
            wf[j] = *(const frag8*)&Ws[((wn + j * 16 + mr) * 4 + q) * 8];
#pragma unroll
        for (int i = 0; i < 4; ++i)
#pragma unroll
            for (int j = 0; j < 3; ++j)
                acc[i][j] = __builtin_amdgcn_mfma_f32_16x16x32_bf16(af[i], wf[j], acc[i][j], 0, 0, 0);
    }
    float* Cz = part + (size_t)blockIdx.z * (B_ * L_) * 96;
#pragma unroll
    for (int i = 0; i < 4; ++i)
#pragma unroll
        for (int j = 0; j < 3; ++j) {
            int gn = wn + j * 16 + mr;
#pragma unroll
            for (int e = 0; e < 4; ++e) {
                int gm = m0 + wm + i * 16 + q * 4 + e;
                Cz[(size_t)gm * 96 + gn] = acc[i][j][e];
            }
        }
}

// sum split-K partials -> dbl fp32; cols 0..63 also -> bf16 dt operand
__global__ void reduce_dbl(const float* __restrict__ part, float* __restrict__ dbl,
                           short* __restrict__ dtbf) {
    int idx = blockIdx.x * blockDim.x + threadIdx.x;
    const int T = B_ * L_ * 96;
    if (idx >= T) return;
    float s = 0.f;
#pragma unroll
    for (int z = 0; z < NSPLIT; ++z) s += part[(size_t)z * T + idx];
    dbl[idx] = s;
    int row = idx / 96, col = idx % 96;
    if (col < RR) dtbf[(size_t)row * RR + col] = f2b(s);
}

// depthwise causal conv (K=4) + bias + SiLU; fp32 + bf16 outputs
__global__ void conv_silu_dual(const float* __restrict__ x,
                               const float* __restrict__ w,
                               const float* __restrict__ bias,
                               float* __restrict__ y, short* __restrict__ ybf,
                               int total) {
    int idx = blockIdx.x * blockDim.x + threadIdx.x;
    if (idx >= total) return;
    int d = idx % DI;
    int l = (idx / DI) % L_;
    float acc = bias[d];
#pragma unroll
    for (int k = 0; k < KC; ++k) {
        int ls = l + k - (KC - 1);
        if (ls >= 0) acc += x[idx + (size_t)(ls - l) * DI] * w[d * KC + k];
    }
    float s = 1.f / (1.f + __expf(-acc));
    float v = acc * s;
    y[idx] = v;
    ybf[idx] = f2b(v);
}

__device__ __forceinline__ float softplus2(float raw, float bd2) {
    float x = raw + bd2;
    return (x > 20.f) ? x : log1pf(__expf(x));
}

// Pass A: per-chunk P = prod(dA), S = local scan from h=0. Softplus folded;
// computed delta is stored back into dtm. B-row slice staged in LDS.
__global__ void scan_chunk(const float* __restrict__ u, float* dtm,
                           const float* __restrict__ bdt,
                           const float* __restrict__ dbl,
                           const float* __restrict__ A_log,
                           float* __restrict__ Pbuf, float* __restrict__ Sbuf) {
    __shared__ float BC[CL][32];
    int tid = threadIdx.x;
    int d = blockIdx.x * 256 + tid;
    int bb = blockIdx.y, c = blockIdx.z;
    const int l0 = c * CL;
    {
        int row = tid >> 3, f4 = tid & 7;
        const float* src = dbl + ((size_t)(bb * L_ + l0 + row) * 96 + 64 + f4 * 4);
        *(float4*)&BC[row][f4 * 4] = *(const float4*)src;
    }
    float Av[NS], P[NS], S[NS];
#pragma unroll
    for (int n = 0; n < NS; ++n) {
        Av[n] = -__expf(A_log[d * NS + n]);
        P[n] = 1.f; S[n] = 0.f;
    }
    float bd2 = 2.f * bdt[d];
    __syncthreads();
    const float* up = u + ((size_t)bb * L_ + l0) * DI + d;
    float* dp = dtm + ((size_t)bb * L_ + l0) * DI + d;
    for (int l = 0; l < CL; ++l) {
        float del = softplus2(dp[(size_t)l * DI], bd2);
        dp[(size_t)l * DI] = del;
        float du = del * up[(size_t)l * DI];
        const float4* Bp = (const float4*)&BC[l][0];
        float4 b4[4] = {Bp[0], Bp[1], Bp[2], Bp[3]};
        const float* Bv = (const float*)b4;
#pragma unroll
        for (int n = 0; n < NS; ++n) {
            float dA = __expf(del * Av[n]);
            P[n] *= dA;
            S[n] = dA * S[n] + du * Bv[n];
        }
    }
    size_t pb = ((size_t)(bb * NCH + c) * NS) * DI + d;
#pragma unroll
    for (int n = 0; n < NS; ++n) {
        Pbuf[pb + (size_t)n * DI] = P[n];
        Sbuf[pb + (size_t)n * DI] = S[n];
    }
}

// Pass B: compose chunk states sequentially; overwrite Pbuf[c] with h_start[c].
__global__ void scan_combine(float* __restrict__ Pbuf, const float* __restrict__ Sbuf) {
    int idx = blockIdx.x * blockDim.x + threadIdx.x;
    int bb = idx / DI, d = idx % DI;
    float h[NS];
#pragma unroll
    for (int n = 0; n < NS; ++n) h[n] = 0.f;
    for (int c = 0; c < NCH; ++c) {
        size_t pb = ((size_t)(bb * NCH + c) * NS) * DI + d;
#pragma unroll
        for (int n = 0; n < NS; ++n) {
            size_t o = pb + (size_t)n * DI;
            float P = Pbuf[o], S = Sbuf[o];
            Pbuf[o] = h[n];
            h[n] = P * h[n] + S;
        }
    }
}

// Pass C: delta precomputed; B/C staged in LDS. y may alias delta.
__global__ void scan_apply(const float* __restrict__ u, const float* delta,
                           const float* __restrict__ dbl,
                           const float* __restrict__ A_log,
                           const float* __restrict__ Dv,
                           const float* __restrict__ Hbuf,
                           float* y) {
    __shared__ float BC[CL][32];
    int tid = threadIdx.x;
    int d = blockIdx.x * 256 + tid;
    int bb = blockIdx.y, c = blockIdx.z;
    const int l0 = c * CL;
    {
        int row = tid >> 3, f4 = tid & 7;
        const float* src = dbl + ((size_t)(bb * L_ + l0 + row) * 96 + 64 + f4 * 4);
        *(float4*)&BC[row][f4 * 4] = *(const float4*)src;
    }
    float Av[NS], h[NS];
    size_t pb = ((size_t)(bb * NCH + c) * NS) * DI + d;
#pragma unroll
    for (int n = 0; n < NS; ++n) {
        Av[n] = -__expf(A_log[d * NS + n]);
        h[n] = Hbuf[pb + (size_t)n * DI];
    }
    float Dd = Dv[d];
    __syncthreads();
    const float* up = u + ((size_t)bb * L_ + l0) * DI + d;
    const float* dp = delta + ((size_t)bb * L_ + l0) * DI + d;
    float* yp = y + ((size_t)bb * L_ + l0) * DI + d;
    for (int l = 0; l < CL; ++l) {
        float del = dp[(size_t)l * DI];
        float ul = up[(size_t)l * DI];
        float du = del * ul;
        const float4* Bp = (const float4*)&BC[l][0];
        float4 bc8[8] = {Bp[0], Bp[1], Bp[2], Bp[3], Bp[4], Bp[5], Bp[6], Bp[7]};
        const float* Bv = (const float*)bc8;
        float acc = 0.f;
#pragma unroll
        for (int n = 0; n < NS; ++n) {
            float dA = __expf(del * Av[n]);
            h[n] = dA * h[n] + du * Bv[n];
            acc += h[n] * Bv[16 + n];
        }
        yp[(size_t)l * DI] = acc + ul * Dd;
    }
}

// g = (y_f + flip(y_b)) * silu(z); rmsnorm; emit bf16 for the final MFMA GEMM.
__global__ void combine_rms(const float* __restrict__ yf, const float* __restrict__ yb,
                            const float* __restrict__ z,
                            const float* __restrict__ nw,
                            short* __restrict__ g) {
    int row = blockIdx.x;
    int bb = row / L_, l = row % L_;
    int tid = threadIdx.x;
    size_t base = (size_t)row * DI;
    size_t baseb = ((size_t)bb * L_ + (L_ - 1 - l)) * DI;
    float gv[8];
    float ss = 0.f;
#pragma unroll
    for (int j = 0; j < 8; ++j) {
        int d = tid + j * 256;
        float yy = yf[base + d] + yb[baseb + d];
        float zz = z[base + d];
        float s = zz / (1.f + __expf(-zz));
        float gg = yy * s;
        gv[j] = gg;
        ss += gg * gg;
    }
#pragma unroll
    for (int off = 32; off > 0; off >>= 1) ss += __shfl_down(ss, off, 64);
    __shared__ float red[4];
    if ((tid & 63) == 0) red[tid >> 6] = ss;
    __syncthreads();
    float tot = red[0] + red[1] + red[2] + red[3];
    float rms = rsqrtf(tot / (float)DI + 1e-5f);
#pragma unroll
    for (int j = 0; j < 8; ++j) {
        int d = tid + j * 256;
        g[base + d] = f2b(gv[j] * rms * nw[d]);
    }
}

extern "C" void kernel_launch(void* const* d_in, const int* in_sizes, int n_in,
                              void* d_out, int out_size, void* d_ws, size_t ws_size,
                              hipStream_t stream) {
    const float* a      = (const float*)d_in[0];
    const float* b      = (const float*)d_in[1];
    const float* Wi     = (const float*)d_in[2];
    const float* conv_w = (const float*)d_in[3];
    const float* conv_b = (const float*)d_in[4];
    const float* Wx     = (const float*)d_in[5];
    const float* Wdt    = (const float*)d_in[6];
    const float* bdt    = (const float*)d_in[7];
    const float* A_log  = (const float*)d_in[8];
    const float* Dvec   = (const float*)d_in[9];
    const float* conv_w_b = (const float*)d_in[10];
    const float* conv_b_b = (const float*)d_in[11];
    const float* Wx_b   = (const float*)d_in[12];
    const float* Wdt_b  = (const float*)d_in[13];
    const float* bdt_b  = (const float*)d_in[14];
    const float* A_log_b = (const float*)d_in[15];
    const float* Dvec_b = (const float*)d_in[16];
    const float* Wo     = (const float*)d_in[17];
    const float* nw     = (const float*)d_in[18];
    float* out = (float*)d_out;

    const int M = B_ * L_;              // 2048
    const size_t BLD = (size_t)M * DI;  // 4194304
    const size_t NDBL = (size_t)M * 96; // 196608
    float* f = (float*)d_ws;
    float* B1   = f;                    // x_f -> dt/delta_f -> y_f
    float* B2   = B1 + BLD;             // u_f -> x_b -> dt/delta_b -> y_b
    float* B3   = B2 + BLD;             // u_b -> z
    float* dblf = B3 + BLD;
    float* dblb = dblf + NDBL;
    float* part = dblb + NDBL;                       // NSPLIT*NDBL
    float* Pbuf = part + (size_t)NSPLIT * NDBL;
    float* Sbuf = Pbuf + (size_t)NCH * B_ * NS * DI;
    short* abf   = (short*)(Sbuf + (size_t)NCH * B_ * NS * DI);
    short* bbf   = abf + (size_t)M * DM;             // also gbf later
    short* Wibf  = bbf + (size_t)M * DM;
    short* cbf   = Wibf + (size_t)2 * DI * DM;
    short* Wxbf  = cbf + BLD;
    short* Wxbbf = Wxbf + (size_t)96 * DI;
    short* Wdtbf = Wxbbf + (size_t)96 * DI;
    short* Wdtbbf= Wdtbf + (size_t)DI * RR;
    short* dtbf  = Wdtbbf + (size_t)DI * RR;
    short* Wobf  = dtbf + (size_t)M * RR;
    short* gbf   = bbf;

    dim3 blk(256);
    const int totBLD = M * DI;
    dim3 scanGrid(DI / 256, B_, NCH);
    const int nWeights = 2 * 96 * DI + 2 * DI * RR + DM * DI;

    // ---- casts ----
    cvt_bf16<<<dim3(M * DM / 256), blk, 0, stream>>>(a, abf, M, DM, L_, 0);
    cvt_bf16<<<dim3(M * DM / 256), blk, 0, stream>>>(b, bbf, M, DM, L_, 1);
    cvt_bf16<<<dim3(2 * DI * DM / 256), blk, 0, stream>>>(Wi, Wibf, 2 * DI, DM, L_, 0);
    cvt_weights<<<dim3((nWeights + 255) / 256), blk, 0, stream>>>(
        Wx, Wx_b, Wdt, Wdt_b, Wo, Wxbf, Wxbbf, Wdtbf, Wdtbbf, Wobf);

    // ---- forward branch ----
    gemm_mfma<128><<<dim3(DI / 64, M / 128), blk, 0, stream>>>(abf, DM, Wibf, DM, 0, B1, DI, DM);
    conv_silu_dual<<<dim3(totBLD / 256), blk, 0, stream>>>(B1, conv_w, conv_b, B2, cbf, totBLD);
    gemm_mfma_dbl<<<dim3(1, M / 128, NSPLIT), blk, 0, stream>>>(cbf, DI, Wxbf, DI, part, DI / NSPLIT);
    reduce_dbl<<<dim3((int)(NDBL / 256)), blk, 0, stream>>>(part, dblf, dtbf);
    gemm_mfma<64><<<dim3(DI / 64, M / 64), blk, 0, stream>>>(dtbf, RR, Wdtbf, RR, 0, B1, DI, RR);
    scan_chunk<<<scanGrid, blk, 0, stream>>>(B2, B1, bdt, dblf, A_log, Pbuf, Sbuf);
    scan_combine<<<dim3(B_ * DI / 256), blk, 0, stream>>>(Pbuf, Sbuf);
    scan_apply<<<scanGrid, blk, 0, stream>>>(B2, B1, dblf, A_log, Dvec, Pbuf, B1);

    // ---- backward branch ----
    gemm_mfma<128><<<dim3(DI / 64, M / 128), blk, 0, stream>>>(bbf, DM, Wibf, DM, 0, B2, DI, DM);
    conv_silu_dual<<<dim3(totBLD / 256), blk, 0, stream>>>(B2, conv_w_b, conv_b_b, B3, cbf, totBLD);
    gemm_mfma_dbl<<<dim3(1, M / 128, NSPLIT), blk, 0, stream>>>(cbf, DI, Wxbbf, DI, part, DI / NSPLIT);
    reduce_dbl<<<dim3((int)(NDBL / 256)), blk, 0, stream>>>(part, dblb, dtbf);
    gemm_mfma<64><<<dim3(DI / 64, M / 64), blk, 0, stream>>>(dtbf, RR, Wdtbbf, RR, 0, B2, DI, RR);
    scan_chunk<<<scanGrid, blk, 0, stream>>>(B3, B2, bdt_b, dblb, A_log_b, Pbuf, Sbuf);
    scan_combine<<<dim3(B_ * DI / 256), blk, 0, stream>>>(Pbuf, Sbuf);
    scan_apply<<<scanGrid, blk, 0, stream>>>(B3, B2, dblb, A_log_b, Dvec_b, Pbuf, B2);

    // ---- combine ----
    gemm_mfma<128><<<dim3(DI / 64, M / 128), blk, 0, stream>>>(abf, DM, Wibf, DM, DI, B3, DI, DM);
    combine_rms<<<dim3(M), blk, 0, stream>>>(B1, B2, B3, nw, gbf);
    gemm_mfma<64><<<dim3(DM / 64, M / 64), blk, 0, stream>>>(gbf, DI, Wobf, DI, 0, out, DM, DI);
}

// Round 9
// 461.046 us; speedup vs baseline: 6.1529x; 1.0632x over previous
//
#include <hip/hip_runtime.h>
#include <hip/hip_bf16.h>
#include <cmath>

#define B_ 2
#define L_ 1024
#define DM 1024
#define DI 2048
#define NS 16
#define RR 64
#define KC 4
#define NCH 32
#define CL (L_ / NCH)   // 32
#define NSPLIT 16       // dbl GEMM split-K factor

using frag8 = __attribute__((ext_vector_type(8))) short;   // 8 bf16 (4 VGPRs)
using facc4 = __attribute__((ext_vector_type(4))) float;   // MFMA C/D

__device__ __forceinline__ short f2b(float v) {
    __hip_bfloat16 h = __float2bfloat16(v);
    return *(short*)&h;
}

// async global->LDS DMA, 16 B per lane. LDS dest is wave-uniform base + lane*16.
__device__ __forceinline__ void async_ld16(const void* g, void* l) {
    __builtin_amdgcn_global_load_lds(
        (const __attribute__((address_space(1))) unsigned int*)g,
        (__attribute__((address_space(3))) unsigned int*)l, 16, 0, 0);
}

// fp32 -> bf16 cast; optional per-batch flip along L (rows = b*Lseq + l)
__global__ void cvt_bf16(const float* __restrict__ x, short* __restrict__ y,
                         int rows, int cols, int Lseq, int flip) {
    int idx = blockIdx.x * blockDim.x + threadIdx.x;
    if (idx >= rows * cols) return;
    int r = idx / cols, c = idx % cols;
    int sr = r;
    if (flip) { int bb = r / Lseq, ll = r % Lseq; sr = bb * Lseq + (Lseq - 1 - ll); }
    y[(size_t)r * cols + c] = f2b(x[(size_t)sr * cols + c]);
}

// one launch converting all the small weights
__global__ void cvt_weights(const float* __restrict__ Wx, const float* __restrict__ Wxb,
                            const float* __restrict__ Wdt, const float* __restrict__ Wdtb,
                            const float* __restrict__ Wo,
                            short* __restrict__ oWx, short* __restrict__ oWxb,
                            short* __restrict__ oWdt, short* __restrict__ oWdtb,
                            short* __restrict__ oWo) {
    int i = blockIdx.x * blockDim.x + threadIdx.x;
    const int S0 = 96 * DI, S2 = DI * RR, S4 = DM * DI;
    if (i < S0) { oWx[i] = f2b(Wx[i]); return; } i -= S0;
    if (i < S0) { oWxb[i] = f2b(Wxb[i]); return; } i -= S0;
    if (i < S2) { oWdt[i] = f2b(Wdt[i]); return; } i -= S2;
    if (i < S2) { oWdtb[i] = f2b(Wdtb[i]); return; } i -= S2;
    if (i < S4) { oWo[i] = f2b(Wo[i]); }
}

// MFMA bf16 GEMM: C[M,N] = A[M,K] * W[N,K]^T, tile BM x 64, BK=32,
// double-buffered LDS: sync -> prefetch(next into other buf) -> compute(cur).
template <int BM>
__global__ __launch_bounds__(256) void gemm_mfma(
    const short* __restrict__ A, int lda,
    const short* __restrict__ W, int ldw, int wRowOff,
    float* __restrict__ C, int ldc, int K) {
    constexpr int MF = BM / 32;
    __shared__ __align__(16) short As[2][BM * 32];
    __shared__ __align__(16) short Ws[2][64 * 32];
    const int tid = threadIdx.x;
    const int lane = tid & 63, wv = tid >> 6;
    const int m0 = blockIdx.y * BM, n0 = blockIdx.x * 64;
    const int wm = (wv & 1) * (BM / 2), wn = (wv >> 1) * 32;
    const int q = lane >> 4, mr = lane & 15;
    const int srow = lane >> 2, skb = lane & 3;

    const short* Ag = A + (size_t)(m0 + wv * 16 + srow) * lda + skb * 8;
    const short* Wg = W + (size_t)(n0 + wRowOff + wv * 16 + srow) * ldw + skb * 8;

    facc4 acc[MF][2];
#pragma unroll
    for (int i = 0; i < MF; ++i)
#pragma unroll
        for (int j = 0; j < 2; ++j) acc[i][j] = (facc4){0.f, 0.f, 0.f, 0.f};

    // prefetch tile 0 -> buf 0
    async_ld16(Ag, &As[0][wv * 512]);
    if constexpr (BM == 128) async_ld16(Ag + (size_t)64 * lda, &As[0][wv * 512 + 2048]);
    async_ld16(Wg, &Ws[0][wv * 512]);

    const int nk = K / 32;
    for (int it = 0; it < nk; ++it) {
        const int buf = it & 1;
        __syncthreads();   // drains DMA(tile it); all waves done reading buf^1
        if (it + 1 < nk) {
            int k0 = (it + 1) * 32;
            async_ld16(Ag + k0, &As[buf ^ 1][wv * 512]);
            if constexpr (BM == 128)
                async_ld16(Ag + (size_t)64 * lda + k0, &As[buf ^ 1][wv * 512 + 2048]);
            async_ld16(Wg + k0, &Ws[buf ^ 1][wv * 512]);
        }
        frag8 af[MF], wf[2];
#pragma unroll
        for (int t = 0; t < MF; ++t)
            af[t] = *(const frag8*)&As[buf][((wm + t * 16 + mr) * 4 + q) * 8];
#pragma unroll
        for (int j = 0; j < 2; ++j)
            wf[j] = *(const frag8*)&Ws[buf][((wn + j * 16 + mr) * 4 + q) * 8];
#pragma unroll
        for (int i = 0; i < MF; ++i)
#pragma unroll
            for (int j = 0; j < 2; ++j)
                acc[i][j] = __builtin_amdgcn_mfma_f32_16x16x32_bf16(af[i], wf[j], acc[i][j], 0, 0, 0);
    }
#pragma unroll
    for (int i = 0; i < MF; ++i)
#pragma unroll
        for (int j = 0; j < 2; ++j) {
            int gn = n0 + wn + j * 16 + mr;
#pragma unroll
            for (int e = 0; e < 4; ++e) {
                int gm = m0 + wm + i * 16 + q * 4 + e;
                C[(size_t)gm * ldc + gn] = acc[i][j][e];
            }
        }
}

// dbl GEMM: part[z][M][96] = A[M, kchunk] * W[96, kchunk]^T (tile 128x96, split-K, dbuf)
__global__ __launch_bounds__(256) void gemm_mfma_dbl(
    const short* __restrict__ A, int lda,
    const short* __restrict__ W, int ldw,
    float* __restrict__ part, int Kchunk) {
    __shared__ __align__(16) short As[2][128 * 32];
    __shared__ __align__(16) short Ws[2][96 * 32];
    const int tid = threadIdx.x;
    const int lane = tid & 63, wv = tid >> 6;
    const int m0 = blockIdx.y * 128;
    const int kOff = blockIdx.z * Kchunk;
    const int wm = (wv & 1) * 64, wn = (wv >> 1) * 48;
    const int q = lane >> 4, mr = lane & 15;
    const int srow = lane >> 2, skb = lane & 3;

    const short* Ag = A + (size_t)(m0 + wv * 16 + srow) * lda + skb * 8 + kOff;
    const short* Wg = W + (size_t)(wv * 16 + srow) * ldw + skb * 8 + kOff;

    facc4 acc[4][3];
#pragma unroll
    for (int i = 0; i < 4; ++i)
#pragma unroll
        for (int j = 0; j < 3; ++j) acc[i][j] = (facc4){0.f, 0.f, 0.f, 0.f};

    async_ld16(Ag, &As[0][wv * 512]);
    async_ld16(Ag + (size_t)64 * lda, &As[0][wv * 512 + 2048]);
    async_ld16(Wg, &Ws[0][wv * 512]);
    if (wv < 2) async_ld16(Wg + (size_t)64 * ldw, &Ws[0][wv * 512 + 2048]);

    const int nk = Kchunk / 32;
    for (int it = 0; it < nk; ++it) {
        const int buf = it & 1;
        __syncthreads();
        if (it + 1 < nk) {
            int k0 = (it + 1) * 32;
            async_ld16(Ag + k0, &As[buf ^ 1][wv * 512]);
            async_ld16(Ag + (size_t)64 * lda + k0, &As[buf ^ 1][wv * 512 + 2048]);
            async_ld16(Wg + k0, &Ws[buf ^ 1][wv * 512]);
            if (wv < 2) async_ld16(Wg + (size_t)64 * ldw + k0, &Ws[buf ^ 1][wv * 512 + 2048]);
        }
        frag8 af[4], wf[3];
#pragma unroll
        for (int t = 0; t < 4; ++t)
            af[t] = *(const frag8*)&As[buf][((wm + t * 16 + mr) * 4 + q) * 8];
#pragma unroll
        for (int j = 0; j < 3; ++j)
            wf[j] = *(const frag8*)&Ws[buf][((wn + j * 16 + mr) * 4 + q) * 8];
#pragma unroll
        for (int i = 0; i < 4; ++i)
#pragma unroll
            for (int j = 0; j < 3; ++j)
                acc[i][j] = __builtin_amdgcn_mfma_f32_16x16x32_bf16(af[i], wf[j], acc[i][j], 0, 0, 0);
    }
    float* Cz = part + (size_t)blockIdx.z * (B_ * L_) * 96;
#pragma unroll
    for (int i = 0; i < 4; ++i)
#pragma unroll
        for (int j = 0; j < 3; ++j) {
            int gn = wn + j * 16 + mr;
#pragma unroll
            for (int e = 0; e < 4; ++e) {
                int gm = m0 + wm + i * 16 + q * 4 + e;
                Cz[(size_t)gm * 96 + gn] = acc[i][j][e];
            }
        }
}

// sum split-K partials -> dbl fp32; cols 0..63 also -> bf16 dt operand
__global__ void reduce_dbl(const float* __restrict__ part, float* __restrict__ dbl,
                           short* __restrict__ dtbf) {
    int idx = blockIdx.x * blockDim.x + threadIdx.x;
    const int T = B_ * L_ * 96;
    if (idx >= T) return;
    float s = 0.f;
#pragma unroll
    for (int z = 0; z < NSPLIT; ++z) s += part[(size_t)z * T + idx];
    dbl[idx] = s;
    int row = idx / 96, col = idx % 96;
    if (col < RR) dtbf[(size_t)row * RR + col] = f2b(s);
}

// depthwise causal conv (K=4) + bias + SiLU; fp32 + bf16 outputs
__global__ void conv_silu_dual(const float* __restrict__ x,
                               const float* __restrict__ w,
                               const float* __restrict__ bias,
                               float* __restrict__ y, short* __restrict__ ybf,
                               int total) {
    int idx = blockIdx.x * blockDim.x + threadIdx.x;
    if (idx >= total) return;
    int d = idx % DI;
    int l = (idx / DI) % L_;
    float acc = bias[d];
#pragma unroll
    for (int k = 0; k < KC; ++k) {
        int ls = l + k - (KC - 1);
        if (ls >= 0) acc += x[idx + (size_t)(ls - l) * DI] * w[d * KC + k];
    }
    float s = 1.f / (1.f + __expf(-acc));
    float v = acc * s;
    y[idx] = v;
    ybf[idx] = f2b(v);
}

__device__ __forceinline__ float softplus2(float raw, float bd2) {
    float x = raw + bd2;
    return (x > 20.f) ? x : log1pf(__expf(x));
}

// Pass A: 2 threads per d, 8 states each. P=prod(dA), S=local scan from h=0.
// Softplus folded; computed delta stored back into dtm (half 0 writes).
__global__ void scan_chunk(const float* __restrict__ u, float* dtm,
                           const float* __restrict__ bdt,
                           const float* __restrict__ dbl,
                           const float* __restrict__ A_log,
                           float* __restrict__ Pbuf, float* __restrict__ Sbuf) {
    __shared__ float Bsh[CL][16];
    const int tid = threadIdx.x;
    const int wv = tid >> 6, lane = tid & 63;
    const int half = lane >> 5;
    const int d = blockIdx.x * 128 + wv * 32 + (lane & 31);
    const int bb = blockIdx.y, c = blockIdx.z;
    const int l0 = c * CL;
    {
        int e = tid * 2;           // CL*16 = 512 floats, 2 per thread
        int row = e >> 4, cc = e & 15;
        *(float2*)&Bsh[row][cc] =
            *(const float2*)(dbl + ((size_t)(bb * L_ + l0 + row) * 96 + 64 + cc));
    }
    float Av[8], P[8], S[8];
#pragma unroll
    for (int j = 0; j < 8; ++j) {
        Av[j] = -__expf(A_log[d * NS + half * 8 + j]);
        P[j] = 1.f; S[j] = 0.f;
    }
    float bd2 = 2.f * bdt[d];
    __syncthreads();
    const float* up = u + ((size_t)bb * L_ + l0) * DI + d;
    float* dp = dtm + ((size_t)bb * L_ + l0) * DI + d;
    for (int l = 0; l < CL; ++l) {
        float del = softplus2(dp[(size_t)l * DI], bd2);
        if (half == 0) dp[(size_t)l * DI] = del;   // read-before-write, wave-lockstep safe
        float du = del * up[(size_t)l * DI];
        float4 b0 = *(const float4*)&Bsh[l][half * 8];
        float4 b1 = *(const float4*)&Bsh[l][half * 8 + 4];
        float Bv[8] = {b0.x, b0.y, b0.z, b0.w, b1.x, b1.y, b1.z, b1.w};
#pragma unroll
        for (int j = 0; j < 8; ++j) {
            float dA = __expf(del * Av[j]);
            P[j] *= dA;
            S[j] = dA * S[j] + du * Bv[j];
        }
    }
    size_t pb = ((size_t)(bb * NCH + c) * NS + half * 8) * DI + d;
#pragma unroll
    for (int j = 0; j < 8; ++j) {
        Pbuf[pb + (size_t)j * DI] = P[j];
        Sbuf[pb + (size_t)j * DI] = S[j];
    }
}

// Pass B: one thread per (b,n,d); sequential over chunks. Pbuf[c] <- h_start[c].
__global__ void scan_combine(float* __restrict__ Pbuf, const float* __restrict__ Sbuf) {
    int g = blockIdx.x * blockDim.x + threadIdx.x;   // B_*NS*DI threads
    int d = g % DI;
    int rest = g / DI;
    int n = rest % NS, bb = rest / NS;
    float h = 0.f;
    for (int c = 0; c < NCH; ++c) {
        size_t o = ((size_t)(bb * NCH + c) * NS + n) * DI + d;
        float P = Pbuf[o], S = Sbuf[o];
        Pbuf[o] = h;
        h = P * h + S;
    }
}

// Pass C: 2 threads per d; C-dot combined via shfl_xor(32). y may alias delta.
__global__ void scan_apply(const float* __restrict__ u, const float* delta,
                           const float* __restrict__ dbl,
                           const float* __restrict__ A_log,
                           const float* __restrict__ Dv,
                           const float* __restrict__ Hbuf,
                           float* y) {
    __shared__ float BC[CL][32];
    const int tid = threadIdx.x;
    const int wv = tid >> 6, lane = tid & 63;
    const int half = lane >> 5;
    const int d = blockIdx.x * 128 + wv * 32 + (lane & 31);
    const int bb = blockIdx.y, c = blockIdx.z;
    const int l0 = c * CL;
    {
        int e = tid * 4;           // CL*32 = 1024 floats, 4 per thread
        int row = e >> 5, cc = e & 31;
        *(float4*)&BC[row][cc] =
            *(const float4*)(dbl + ((size_t)(bb * L_ + l0 + row) * 96 + 64 + cc));
    }
    float Av[8], h[8];
    size_t pb = ((size_t)(bb * NCH + c) * NS + half * 8) * DI + d;
#pragma unroll
    for (int j = 0; j < 8; ++j) {
        Av[j] = -__expf(A_log[d * NS + half * 8 + j]);
        h[j] = Hbuf[pb + (size_t)j * DI];
    }
    float Dd = Dv[d];
    __syncthreads();
    const float* up = u + ((size_t)bb * L_ + l0) * DI + d;
    const float* dp = delta + ((size_t)bb * L_ + l0) * DI + d;
    float* yp = y + ((size_t)bb * L_ + l0) * DI + d;
    for (int l = 0; l < CL; ++l) {
        float del = dp[(size_t)l * DI];
        float ul = up[(size_t)l * DI];
        float du = del * ul;
        float4 b0 = *(const float4*)&BC[l][half * 8];
        float4 b1 = *(const float4*)&BC[l][half * 8 + 4];
        float4 c0 = *(const float4*)&BC[l][16 + half * 8];
        float4 c1 = *(const float4*)&BC[l][16 + half * 8 + 4];
        float Bv[8] = {b0.x, b0.y, b0.z, b0.w, b1.x, b1.y, b1.z, b1.w};
        float Cv[8] = {c0.x, c0.y, c0.z, c0.w, c1.x, c1.y, c1.z, c1.w};
        float acc = 0.f;
#pragma unroll
        for (int j = 0; j < 8; ++j) {
            float dA = __expf(del * Av[j]);
            h[j] = dA * h[j] + du * Bv[j];
            acc += h[j] * Cv[j];
        }
        acc += __shfl_xor(acc, 32, 64);
        if (half == 0) yp[(size_t)l * DI] = acc + ul * Dd;
    }
}

// g = (y_f + flip(y_b)) * silu(z); rmsnorm; emit bf16 for the final MFMA GEMM.
__global__ void combine_rms(const float* __restrict__ yf, const float* __restrict__ yb,
                            const float* __restrict__ z,
                            const float* __restrict__ nw,
                            short* __restrict__ g) {
    int row = blockIdx.x;
    int bb = row / L_, l = row % L_;
    int tid = threadIdx.x;
    size_t base = (size_t)row * DI;
    size_t baseb = ((size_t)bb * L_ + (L_ - 1 - l)) * DI;
    float gv[8];
    float ss = 0.f;
#pragma unroll
    for (int j = 0; j < 8; ++j) {
        int d = tid + j * 256;
        float yy = yf[base + d] + yb[baseb + d];
        float zz = z[base + d];
        float s = zz / (1.f + __expf(-zz));
        float gg = yy * s;
        gv[j] = gg;
        ss += gg * gg;
    }
#pragma unroll
    for (int off = 32; off > 0; off >>= 1) ss += __shfl_down(ss, off, 64);
    __shared__ float red[4];
    if ((tid & 63) == 0) red[tid >> 6] = ss;
    __syncthreads();
    float tot = red[0] + red[1] + red[2] + red[3];
    float rms = rsqrtf(tot / (float)DI + 1e-5f);
#pragma unroll
    for (int j = 0; j < 8; ++j) {
        int d = tid + j * 256;
        g[base + d] = f2b(gv[j] * rms * nw[d]);
    }
}

extern "C" void kernel_launch(void* const* d_in, const int* in_sizes, int n_in,
                              void* d_out, int out_size, void* d_ws, size_t ws_size,
                              hipStream_t stream) {
    const float* a      = (const float*)d_in[0];
    const float* b      = (const float*)d_in[1];
    const float* Wi     = (const float*)d_in[2];
    const float* conv_w = (const float*)d_in[3];
    const float* conv_b = (const float*)d_in[4];
    const float* Wx     = (const float*)d_in[5];
    const float* Wdt    = (const float*)d_in[6];
    const float* bdt    = (const float*)d_in[7];
    const float* A_log  = (const float*)d_in[8];
    const float* Dvec   = (const float*)d_in[9];
    const float* conv_w_b = (const float*)d_in[10];
    const float* conv_b_b = (const float*)d_in[11];
    const float* Wx_b   = (const float*)d_in[12];
    const float* Wdt_b  = (const float*)d_in[13];
    const float* bdt_b  = (const float*)d_in[14];
    const float* A_log_b = (const float*)d_in[15];
    const float* Dvec_b = (const float*)d_in[16];
    const float* Wo     = (const float*)d_in[17];
    const float* nw     = (const float*)d_in[18];
    float* out = (float*)d_out;

    const int M = B_ * L_;              // 2048
    const size_t BLD = (size_t)M * DI;  // 4194304
    const size_t NDBL = (size_t)M * 96; // 196608
    float* f = (float*)d_ws;
    float* B1   = f;                    // x_f -> dt/delta_f -> y_f
    float* B2   = B1 + BLD;             // u_f -> x_b -> dt/delta_b -> y_b
    float* B3   = B2 + BLD;             // u_b -> z
    float* dblf = B3 + BLD;
    float* dblb = dblf + NDBL;
    float* part = dblb + NDBL;                       // NSPLIT*NDBL
    float* Pbuf = part + (size_t)NSPLIT * NDBL;
    float* Sbuf = Pbuf + (size_t)NCH * B_ * NS * DI;
    short* abf   = (short*)(Sbuf + (size_t)NCH * B_ * NS * DI);
    short* bbf   = abf + (size_t)M * DM;             // also gbf later
    short* Wibf  = bbf + (size_t)M * DM;
    short* cbf   = Wibf + (size_t)2 * DI * DM;
    short* Wxbf  = cbf + BLD;
    short* Wxbbf = Wxbf + (size_t)96 * DI;
    short* Wdtbf = Wxbbf + (size_t)96 * DI;
    short* Wdtbbf= Wdtbf + (size_t)DI * RR;
    short* dtbf  = Wdtbbf + (size_t)DI * RR;
    short* Wobf  = dtbf + (size_t)M * RR;
    short* gbf   = bbf;

    dim3 blk(256);
    const int totBLD = M * DI;
    dim3 scanGrid(DI / 128, B_, NCH);
    const int nWeights = 2 * 96 * DI + 2 * DI * RR + DM * DI;

    // ---- casts ----
    cvt_bf16<<<dim3(M * DM / 256), blk, 0, stream>>>(a, abf, M, DM, L_, 0);
    cvt_bf16<<<dim3(M * DM / 256), blk, 0, stream>>>(b, bbf, M, DM, L_, 1);
    cvt_bf16<<<dim3(2 * DI * DM / 256), blk, 0, stream>>>(Wi, Wibf, 2 * DI, DM, L_, 0);
    cvt_weights<<<dim3((nWeights + 255) / 256), blk, 0, stream>>>(
        Wx, Wx_b, Wdt, Wdt_b, Wo, Wxbf, Wxbbf, Wdtbf, Wdtbbf, Wobf);

    // ---- forward branch ----
    gemm_mfma<128><<<dim3(DI / 64, M / 128), blk, 0, stream>>>(abf, DM, Wibf, DM, 0, B1, DI, DM);
    conv_silu_dual<<<dim3(totBLD / 256), blk, 0, stream>>>(B1, conv_w, conv_b, B2, cbf, totBLD);
    gemm_mfma_dbl<<<dim3(1, M / 128, NSPLIT), blk, 0, stream>>>(cbf, DI, Wxbf, DI, part, DI / NSPLIT);
    reduce_dbl<<<dim3((int)(NDBL / 256)), blk, 0, stream>>>(part, dblf, dtbf);
    gemm_mfma<64><<<dim3(DI / 64, M / 64), blk, 0, stream>>>(dtbf, RR, Wdtbf, RR, 0, B1, DI, RR);
    scan_chunk<<<scanGrid, blk, 0, stream>>>(B2, B1, bdt, dblf, A_log, Pbuf, Sbuf);
    scan_combine<<<dim3(B_ * NS * DI / 256), blk, 0, stream>>>(Pbuf, Sbuf);
    scan_apply<<<scanGrid, blk, 0, stream>>>(B2, B1, dblf, A_log, Dvec, Pbuf, B1);

    // ---- backward branch ----
    gemm_mfma<128><<<dim3(DI / 64, M / 128), blk, 0, stream>>>(bbf, DM, Wibf, DM, 0, B2, DI, DM);
    conv_silu_dual<<<dim3(totBLD / 256), blk, 0, stream>>>(B2, conv_w_b, conv_b_b, B3, cbf, totBLD);
    gemm_mfma_dbl<<<dim3(1, M / 128, NSPLIT), blk, 0, stream>>>(cbf, DI, Wxbbf, DI, part, DI / NSPLIT);
    reduce_dbl<<<dim3((int)(NDBL / 256)), blk, 0, stream>>>(part, dblb, dtbf);
    gemm_mfma<64><<<dim3(DI / 64, M / 64), blk, 0, stream>>>(dtbf, RR, Wdtbbf, RR, 0, B2, DI, RR);
    scan_chunk<<<scanGrid, blk, 0, stream>>>(B3, B2, bdt_b, dblb, A_log_b, Pbuf, Sbuf);
    scan_combine<<<dim3(B_ * NS * DI / 256), blk, 0, stream>>>(Pbuf, Sbuf);
    scan_apply<<<scanGrid, blk, 0, stream>>>(B3, B2, dblb, A_log_b, Dvec_b, Pbuf, B2);

    // ---- combine ----
    gemm_mfma<128><<<dim3(DI / 64, M / 128), blk, 0, stream>>>(abf, DM, Wibf, DM, DI, B3, DI, DM);
    combine_rms<<<dim3(M), blk, 0, stream>>>(B1, B2, B3, nw, gbf);
    gemm_mfma<64><<<dim3(DM / 64, M / 64), blk, 0, stream>>>(gbf, DI, Wobf, DI, 0, out, DM, DI);
}

// Round 10
// 427.509 us; speedup vs baseline: 6.6356x; 1.0784x over previous
//
#include <hip/hip_runtime.h>
#include <hip/hip_bf16.h>
#include <cmath>

#define B_ 2
#define L_ 1024
#define DM 1024
#define DI 2048
#define NS 16
#define RR 64
#define KC 4
#define NCH 32
#define CL (L_ / NCH)   // 32
#define NSPLIT 16       // dbl GEMM split-K factor

using frag8 = __attribute__((ext_vector_type(8))) short;   // 8 bf16 (4 VGPRs)
using facc4 = __attribute__((ext_vector_type(4))) float;   // MFMA C/D

__device__ __forceinline__ short f2b(float v) {
    __hip_bfloat16 h = __float2bfloat16(v);
    return *(short*)&h;
}

// async global->LDS DMA, 16 B per lane. LDS dest is wave-uniform base + lane*16.
__device__ __forceinline__ void async_ld16(const void* g, void* l) {
    __builtin_amdgcn_global_load_lds(
        (const __attribute__((address_space(1))) unsigned int*)g,
        (__attribute__((address_space(3))) unsigned int*)l, 16, 0, 0);
}

// fp32 -> bf16 cast; optional per-batch flip along L (rows = b*Lseq + l)
__global__ void cvt_bf16(const float* __restrict__ x, short* __restrict__ y,
                         int rows, int cols, int Lseq, int flip) {
    int idx = blockIdx.x * blockDim.x + threadIdx.x;
    if (idx >= rows * cols) return;
    int r = idx / cols, c = idx % cols;
    int sr = r;
    if (flip) { int bb = r / Lseq, ll = r % Lseq; sr = bb * Lseq + (Lseq - 1 - ll); }
    y[(size_t)r * cols + c] = f2b(x[(size_t)sr * cols + c]);
}

// one launch converting all the small weights
__global__ void cvt_weights(const float* __restrict__ Wx, const float* __restrict__ Wxb,
                            const float* __restrict__ Wdt, const float* __restrict__ Wdtb,
                            const float* __restrict__ Wo,
                            short* __restrict__ oWx, short* __restrict__ oWxb,
                            short* __restrict__ oWdt, short* __restrict__ oWdtb,
                            short* __restrict__ oWo) {
    int i = blockIdx.x * blockDim.x + threadIdx.x;
    const int S0 = 96 * DI, S2 = DI * RR, S4 = DM * DI;
    if (i < S0) { oWx[i] = f2b(Wx[i]); return; } i -= S0;
    if (i < S0) { oWxb[i] = f2b(Wxb[i]); return; } i -= S0;
    if (i < S2) { oWdt[i] = f2b(Wdt[i]); return; } i -= S2;
    if (i < S2) { oWdtb[i] = f2b(Wdtb[i]); return; } i -= S2;
    if (i < S4) { oWo[i] = f2b(Wo[i]); }
}

// MFMA bf16 GEMM: C[M,N] = A[M,K] * W[N,K]^T, tile BM x 64, BK=32,
// double-buffered LDS: sync -> prefetch(next into other buf) -> compute(cur).
template <int BM>
__global__ __launch_bounds__(256) void gemm_mfma(
    const short* __restrict__ A, int lda,
    const short* __restrict__ W, int ldw, int wRowOff,
    float* __restrict__ C, int ldc, int K) {
    constexpr int MF = BM / 32;
    __shared__ __align__(16) short As[2][BM * 32];
    __shared__ __align__(16) short Ws[2][64 * 32];
    const int tid = threadIdx.x;
    const int lane = tid & 63, wv = tid >> 6;
    const int m0 = blockIdx.y * BM, n0 = blockIdx.x * 64;
    const int wm = (wv & 1) * (BM / 2), wn = (wv >> 1) * 32;
    const int q = lane >> 4, mr = lane & 15;
    const int srow = lane >> 2, skb = lane & 3;

    const short* Ag = A + (size_t)(m0 + wv * 16 + srow) * lda + skb * 8;
    const short* Wg = W + (size_t)(n0 + wRowOff + wv * 16 + srow) * ldw + skb * 8;

    facc4 acc[MF][2];
#pragma unroll
    for (int i = 0; i < MF; ++i)
#pragma unroll
        for (int j = 0; j < 2; ++j) acc[i][j] = (facc4){0.f, 0.f, 0.f, 0.f};

    async_ld16(Ag, &As[0][wv * 512]);
    if constexpr (BM == 128) async_ld16(Ag + (size_t)64 * lda, &As[0][wv * 512 + 2048]);
    async_ld16(Wg, &Ws[0][wv * 512]);

    const int nk = K / 32;
    for (int it = 0; it < nk; ++it) {
        const int buf = it & 1;
        __syncthreads();
        if (it + 1 < nk) {
            int k0 = (it + 1) * 32;
            async_ld16(Ag + k0, &As[buf ^ 1][wv * 512]);
            if constexpr (BM == 128)
                async_ld16(Ag + (size_t)64 * lda + k0, &As[buf ^ 1][wv * 512 + 2048]);
            async_ld16(Wg + k0, &Ws[buf ^ 1][wv * 512]);
        }
        frag8 af[MF], wf[2];
#pragma unroll
        for (int t = 0; t < MF; ++t)
            af[t] = *(const frag8*)&As[buf][((wm + t * 16 + mr) * 4 + q) * 8];
#pragma unroll
        for (int j = 0; j < 2; ++j)
            wf[j] = *(const frag8*)&Ws[buf][((wn + j * 16 + mr) * 4 + q) * 8];
#pragma unroll
        for (int i = 0; i < MF; ++i)
#pragma unroll
            for (int j = 0; j < 2; ++j)
                acc[i][j] = __builtin_amdgcn_mfma_f32_16x16x32_bf16(af[i], wf[j], acc[i][j], 0, 0, 0);
    }
#pragma unroll
    for (int i = 0; i < MF; ++i)
#pragma unroll
        for (int j = 0; j < 2; ++j) {
            int gn = n0 + wn + j * 16 + mr;
#pragma unroll
            for (int e = 0; e < 4; ++e) {
                int gm = m0 + wm + i * 16 + q * 4 + e;
                C[(size_t)gm * ldc + gn] = acc[i][j][e];
            }
        }
}

// dbl GEMM: part[z][M][96] = A[M, kchunk] * W[96, kchunk]^T (tile 128x96, split-K, dbuf)
__global__ __launch_bounds__(256) void gemm_mfma_dbl(
    const short* __restrict__ A, int lda,
    const short* __restrict__ W, int ldw,
    float* __restrict__ part, int Kchunk) {
    __shared__ __align__(16) short As[2][128 * 32];
    __shared__ __align__(16) short Ws[2][96 * 32];
    const int tid = threadIdx.x;
    const int lane = tid & 63, wv = tid >> 6;
    const int m0 = blockIdx.y * 128;
    const int kOff = blockIdx.z * Kchunk;
    const int wm = (wv & 1) * 64, wn = (wv >> 1) * 48;
    const int q = lane >> 4, mr = lane & 15;
    const int srow = lane >> 2, skb = lane & 3;

    const short* Ag = A + (size_t)(m0 + wv * 16 + srow) * lda + skb * 8 + kOff;
    const short* Wg = W + (size_t)(wv * 16 + srow) * ldw + skb * 8 + kOff;

    facc4 acc[4][3];
#pragma unroll
    for (int i = 0; i < 4; ++i)
#pragma unroll
        for (int j = 0; j < 3; ++j) acc[i][j] = (facc4){0.f, 0.f, 0.f, 0.f};

    async_ld16(Ag, &As[0][wv * 512]);
    async_ld16(Ag + (size_t)64 * lda, &As[0][wv * 512 + 2048]);
    async_ld16(Wg, &Ws[0][wv * 512]);
    if (wv < 2) async_ld16(Wg + (size_t)64 * ldw, &Ws[0][wv * 512 + 2048]);

    const int nk = Kchunk / 32;
    for (int it = 0; it < nk; ++it) {
        const int buf = it & 1;
        __syncthreads();
        if (it + 1 < nk) {
            int k0 = (it + 1) * 32;
            async_ld16(Ag + k0, &As[buf ^ 1][wv * 512]);
            async_ld16(Ag + (size_t)64 * lda + k0, &As[buf ^ 1][wv * 512 + 2048]);
            async_ld16(Wg + k0, &Ws[buf ^ 1][wv * 512]);
            if (wv < 2) async_ld16(Wg + (size_t)64 * ldw + k0, &Ws[buf ^ 1][wv * 512 + 2048]);
        }
        frag8 af[4], wf[3];
#pragma unroll
        for (int t = 0; t < 4; ++t)
            af[t] = *(const frag8*)&As[buf][((wm + t * 16 + mr) * 4 + q) * 8];
#pragma unroll
        for (int j = 0; j < 3; ++j)
            wf[j] = *(const frag8*)&Ws[buf][((wn + j * 16 + mr) * 4 + q) * 8];
#pragma unroll
        for (int i = 0; i < 4; ++i)
#pragma unroll
            for (int j = 0; j < 3; ++j)
                acc[i][j] = __builtin_amdgcn_mfma_f32_16x16x32_bf16(af[i], wf[j], acc[i][j], 0, 0, 0);
    }
    float* Cz = part + (size_t)blockIdx.z * (B_ * L_) * 96;
#pragma unroll
    for (int i = 0; i < 4; ++i)
#pragma unroll
        for (int j = 0; j < 3; ++j) {
            int gn = wn + j * 16 + mr;
#pragma unroll
            for (int e = 0; e < 4; ++e) {
                int gm = m0 + wm + i * 16 + q * 4 + e;
                Cz[(size_t)gm * 96 + gn] = acc[i][j][e];
            }
        }
}

// sum split-K partials -> dbl fp32; cols 0..63 also -> bf16 dt operand
__global__ void reduce_dbl(const float* __restrict__ part, float* __restrict__ dbl,
                           short* __restrict__ dtbf) {
    int idx = blockIdx.x * blockDim.x + threadIdx.x;
    const int T = B_ * L_ * 96;
    if (idx >= T) return;
    float s = 0.f;
#pragma unroll
    for (int z = 0; z < NSPLIT; ++z) s += part[(size_t)z * T + idx];
    dbl[idx] = s;
    int row = idx / 96, col = idx % 96;
    if (col < RR) dtbf[(size_t)row * RR + col] = f2b(s);
}

// depthwise causal conv (K=4) + bias + SiLU; fp32 + bf16 outputs
__global__ void conv_silu_dual(const float* __restrict__ x,
                               const float* __restrict__ w,
                               const float* __restrict__ bias,
                               float* __restrict__ y, short* __restrict__ ybf,
                               int total) {
    int idx = blockIdx.x * blockDim.x + threadIdx.x;
    if (idx >= total) return;
    int d = idx % DI;
    int l = (idx / DI) % L_;
    float acc = bias[d];
#pragma unroll
    for (int k = 0; k < KC; ++k) {
        int ls = l + k - (KC - 1);
        if (ls >= 0) acc += x[idx + (size_t)(ls - l) * DI] * w[d * KC + k];
    }
    float s = 1.f / (1.f + __expf(-acc));
    float v = acc * s;
    y[idx] = v;
    ybf[idx] = f2b(v);
}

__device__ __forceinline__ float softplus2(float raw, float bd2) {
    float x = raw + bd2;
    return (x > 20.f) ? x : log1pf(__expf(x));
}

// Pass A (fused local scan): reads u (B-buf) + raw dt (D-buf); writes
//   y_local (+u*D) over u, cumulative-delta over dt, P/S chunk states.
// Exploits A[n] = (n+1)*A[0] (runtime-verified, wave-uniform): dA_n = q^(n+1).
__global__ void scan_chunk(float* u, float* dtm,
                           const float* __restrict__ bdt,
                           const float* __restrict__ dbl,
                           const float* __restrict__ A_log,
                           const float* __restrict__ Dv,
                           float* __restrict__ Pbuf, float* __restrict__ Sbuf) {
    __shared__ float BCs[CL][32];
    const int tid = threadIdx.x;
    const int d = blockIdx.x * 256 + tid;
    const int bb = blockIdx.y, c = blockIdx.z;
    const int l0 = c * CL;
    {
        int e = tid * 4;   // CL*32 = 1024 floats
        int row = e >> 5, cc = e & 31;
        *(float4*)&BCs[row][cc] =
            *(const float4*)(dbl + ((size_t)(bb * L_ + l0 + row) * 96 + 64 + cc));
    }
    float Av[NS], S[NS];
#pragma unroll
    for (int n = 0; n < NS; ++n) { Av[n] = -__expf(A_log[d * NS + n]); S[n] = 0.f; }
    bool structured = true;
#pragma unroll
    for (int n = 1; n < NS; ++n)
        structured = structured &&
            (fabsf(Av[n] - (n + 1) * Av[0]) <= 1e-4f * (n + 1) * fabsf(Av[0]));
    const float bd2 = 2.f * bdt[d];
    const float Dd = Dv[d];
    float cd = 0.f;
    __syncthreads();
    float* up = u + ((size_t)bb * L_ + l0) * DI + d;
    float* dp = dtm + ((size_t)bb * L_ + l0) * DI + d;
    if (structured) {
        const float Av0 = Av[0];
        for (int l = 0; l < CL; ++l) {
            float del = softplus2(dp[(size_t)l * DI], bd2);
            cd += del;
            float ul = up[(size_t)l * DI];
            float du = del * ul;
            float q = __expf(del * Av0);
            float p = q;
            float acc = 0.f;
            const float* Brow = &BCs[l][0];
#pragma unroll
            for (int n = 0; n < NS; ++n) {
                S[n] = p * S[n] + du * Brow[n];
                acc += S[n] * Brow[16 + n];
                p *= q;
            }
            dp[(size_t)l * DI] = cd;
            up[(size_t)l * DI] = acc + ul * Dd;
        }
    } else {
        for (int l = 0; l < CL; ++l) {
            float del = softplus2(dp[(size_t)l * DI], bd2);
            cd += del;
            float ul = up[(size_t)l * DI];
            float du = del * ul;
            float acc = 0.f;
            const float* Brow = &BCs[l][0];
#pragma unroll
            for (int n = 0; n < NS; ++n) {
                float dA = __expf(del * Av[n]);
                S[n] = dA * S[n] + du * Brow[n];
                acc += S[n] * Brow[16 + n];
            }
            dp[(size_t)l * DI] = cd;
            up[(size_t)l * DI] = acc + ul * Dd;
        }
    }
    size_t pb = ((size_t)(bb * NCH + c) * NS) * DI + d;
    if (structured) {
        float r = __expf(cd * Av[0]);
        float p = r;
#pragma unroll
        for (int n = 0; n < NS; ++n) {
            Pbuf[pb + (size_t)n * DI] = p;
            Sbuf[pb + (size_t)n * DI] = S[n];
            p *= r;
        }
    } else {
#pragma unroll
        for (int n = 0; n < NS; ++n) {
            Pbuf[pb + (size_t)n * DI] = __expf(cd * Av[n]);
            Sbuf[pb + (size_t)n * DI] = S[n];
        }
    }
}

// Pass B: one thread per (b,n,d); sequential over chunks. Pbuf[c] <- h_start[c].
__global__ void scan_combine(float* __restrict__ Pbuf, const float* __restrict__ Sbuf) {
    int g = blockIdx.x * blockDim.x + threadIdx.x;   // B_*NS*DI threads
    int d = g % DI;
    int rest = g / DI;
    int n = rest % NS, bb = rest / NS;
    float h = 0.f;
    for (int c = 0; c < NCH; ++c) {
        size_t o = ((size_t)(bb * NCH + c) * NS + n) * DI + d;
        float P = Pbuf[o], S = Sbuf[o];
        Pbuf[o] = h;
        h = P * h + S;
    }
}

// Pass C (correction, no recurrence): y[l] = y_local[l] + sum_n C[l,n]*exp(Av[n]*cd_l)*hs[n].
// Chunk 0 has hs=0 -> grid.z = NCH-1, c = z+1.
__global__ void scan_apply(float* y, const float* __restrict__ cdm,
                           const float* __restrict__ dbl,
                           const float* __restrict__ A_log,
                           const float* __restrict__ Hbuf) {
    __shared__ float Cs[CL][16];
    const int tid = threadIdx.x;
    const int d = blockIdx.x * 256 + tid;
    const int bb = blockIdx.y, c = blockIdx.z + 1;
    const int l0 = c * CL;
    {
        int e = tid * 2;   // CL*16 = 512 floats
        int row = e >> 4, cc = e & 15;
        *(float2*)&Cs[row][cc] =
            *(const float2*)(dbl + ((size_t)(bb * L_ + l0 + row) * 96 + 80 + cc));
    }
    float Av[NS], chs[NS];
#pragma unroll
    for (int n = 0; n < NS; ++n) Av[n] = -__expf(A_log[d * NS + n]);
    bool structured = true;
#pragma unroll
    for (int n = 1; n < NS; ++n)
        structured = structured &&
            (fabsf(Av[n] - (n + 1) * Av[0]) <= 1e-4f * (n + 1) * fabsf(Av[0]));
    size_t pb = ((size_t)(bb * NCH + c) * NS) * DI + d;
#pragma unroll
    for (int n = 0; n < NS; ++n) chs[n] = Hbuf[pb + (size_t)n * DI];
    __syncthreads();
    const float* cp = cdm + ((size_t)bb * L_ + l0) * DI + d;
    float* yp = y + ((size_t)bb * L_ + l0) * DI + d;
    if (structured) {
        const float Av0 = Av[0];
        for (int l = 0; l < CL; ++l) {
            float cd = cp[(size_t)l * DI];
            float r = __expf(cd * Av0);
            float p = r;
            float acc = 0.f;
            const float* Crow = &Cs[l][0];
#pragma unroll
            for (int n = 0; n < NS; ++n) {
                acc += p * Crow[n] * chs[n];
                p *= r;
            }
            yp[(size_t)l * DI] += acc;
        }
    } else {
        for (int l = 0; l < CL; ++l) {
            float cd = cp[(size_t)l * DI];
            float acc = 0.f;
            const float* Crow = &Cs[l][0];
#pragma unroll
            for (int n = 0; n < NS; ++n)
                acc += __expf(cd * Av[n]) * Crow[n] * chs[n];
            yp[(size_t)l * DI] += acc;
        }
    }
}

// g = (y_f + flip(y_b)) * silu(z); rmsnorm; emit bf16 for the final MFMA GEMM.
__global__ void combine_rms(const float* __restrict__ yf, const float* __restrict__ yb,
                            const float* __restrict__ z,
                            const float* __restrict__ nw,
                            short* __restrict__ g) {
    int row = blockIdx.x;
    int bb = row / L_, l = row % L_;
    int tid = threadIdx.x;
    size_t base = (size_t)row * DI;
    size_t baseb = ((size_t)bb * L_ + (L_ - 1 - l)) * DI;
    float gv[8];
    float ss = 0.f;
#pragma unroll
    for (int j = 0; j < 8; ++j) {
        int d = tid + j * 256;
        float yy = yf[base + d] + yb[baseb + d];
        float zz = z[base + d];
        float s = zz / (1.f + __expf(-zz));
        float gg = yy * s;
        gv[j] = gg;
        ss += gg * gg;
    }
#pragma unroll
    for (int off = 32; off > 0; off >>= 1) ss += __shfl_down(ss, off, 64);
    __shared__ float red[4];
    if ((tid & 63) == 0) red[tid >> 6] = ss;
    __syncthreads();
    float tot = red[0] + red[1] + red[2] + red[3];
    float rms = rsqrtf(tot / (float)DI + 1e-5f);
#pragma unroll
    for (int j = 0; j < 8; ++j) {
        int d = tid + j * 256;
        g[base + d] = f2b(gv[j] * rms * nw[d]);
    }
}

extern "C" void kernel_launch(void* const* d_in, const int* in_sizes, int n_in,
                              void* d_out, int out_size, void* d_ws, size_t ws_size,
                              hipStream_t stream) {
    const float* a      = (const float*)d_in[0];
    const float* b      = (const float*)d_in[1];
    const float* Wi     = (const float*)d_in[2];
    const float* conv_w = (const float*)d_in[3];
    const float* conv_b = (const float*)d_in[4];
    const float* Wx     = (const float*)d_in[5];
    const float* Wdt    = (const float*)d_in[6];
    const float* bdt    = (const float*)d_in[7];
    const float* A_log  = (const float*)d_in[8];
    const float* Dvec   = (const float*)d_in[9];
    const float* conv_w_b = (const float*)d_in[10];
    const float* conv_b_b = (const float*)d_in[11];
    const float* Wx_b   = (const float*)d_in[12];
    const float* Wdt_b  = (const float*)d_in[13];
    const float* bdt_b  = (const float*)d_in[14];
    const float* A_log_b = (const float*)d_in[15];
    const float* Dvec_b = (const float*)d_in[16];
    const float* Wo     = (const float*)d_in[17];
    const float* nw     = (const float*)d_in[18];
    float* out = (float*)d_out;

    const int M = B_ * L_;              // 2048
    const size_t BLD = (size_t)M * DI;  // 4194304
    const size_t NDBL = (size_t)M * 96; // 196608
    float* f = (float*)d_ws;
    float* B1   = f;                    // x_f -> cd_f | x_b -> cd_b -> z
    float* B2   = B1 + BLD;             // u_f -> y_f (final)
    float* B3   = B2 + BLD;             // u_b -> y_b (final)
    float* dblf = B3 + BLD;
    float* dblb = dblf + NDBL;
    float* part = dblb + NDBL;                       // NSPLIT*NDBL
    float* Pbuf = part + (size_t)NSPLIT * NDBL;
    float* Sbuf = Pbuf + (size_t)NCH * B_ * NS * DI;
    short* abf   = (short*)(Sbuf + (size_t)NCH * B_ * NS * DI);
    short* bbf   = abf + (size_t)M * DM;             // also gbf later
    short* Wibf  = bbf + (size_t)M * DM;
    short* cbf   = Wibf + (size_t)2 * DI * DM;
    short* Wxbf  = cbf + BLD;
    short* Wxbbf = Wxbf + (size_t)96 * DI;
    short* Wdtbf = Wxbbf + (size_t)96 * DI;
    short* Wdtbbf= Wdtbf + (size_t)DI * RR;
    short* dtbf  = Wdtbbf + (size_t)DI * RR;
    short* Wobf  = dtbf + (size_t)M * RR;
    short* gbf   = bbf;

    dim3 blk(256);
    const int totBLD = M * DI;
    dim3 chunkGrid(DI / 256, B_, NCH);
    dim3 applyGrid(DI / 256, B_, NCH - 1);
    const int nWeights = 2 * 96 * DI + 2 * DI * RR + DM * DI;

    // ---- casts ----
    cvt_bf16<<<dim3(M * DM / 256), blk, 0, stream>>>(a, abf, M, DM, L_, 0);
    cvt_bf16<<<dim3(M * DM / 256), blk, 0, stream>>>(b, bbf, M, DM, L_, 1);
    cvt_bf16<<<dim3(2 * DI * DM / 256), blk, 0, stream>>>(Wi, Wibf, 2 * DI, DM, L_, 0);
    cvt_weights<<<dim3((nWeights + 255) / 256), blk, 0, stream>>>(
        Wx, Wx_b, Wdt, Wdt_b, Wo, Wxbf, Wxbbf, Wdtbf, Wdtbbf, Wobf);

    // ---- forward branch ----
    gemm_mfma<128><<<dim3(DI / 64, M / 128), blk, 0, stream>>>(abf, DM, Wibf, DM, 0, B1, DI, DM);
    conv_silu_dual<<<dim3(totBLD / 256), blk, 0, stream>>>(B1, conv_w, conv_b, B2, cbf, totBLD);
    gemm_mfma_dbl<<<dim3(1, M / 128, NSPLIT), blk, 0, stream>>>(cbf, DI, Wxbf, DI, part, DI / NSPLIT);
    reduce_dbl<<<dim3((int)(NDBL / 256)), blk, 0, stream>>>(part, dblf, dtbf);
    gemm_mfma<64><<<dim3(DI / 64, M / 64), blk, 0, stream>>>(dtbf, RR, Wdtbf, RR, 0, B1, DI, RR);
    scan_chunk<<<chunkGrid, blk, 0, stream>>>(B2, B1, bdt, dblf, A_log, Dvec, Pbuf, Sbuf);
    scan_combine<<<dim3(B_ * NS * DI / 256), blk, 0, stream>>>(Pbuf, Sbuf);
    scan_apply<<<applyGrid, blk, 0, stream>>>(B2, B1, dblf, A_log, Pbuf);

    // ---- backward branch ----
    gemm_mfma<128><<<dim3(DI / 64, M / 128), blk, 0, stream>>>(bbf, DM, Wibf, DM, 0, B1, DI, DM);
    conv_silu_dual<<<dim3(totBLD / 256), blk, 0, stream>>>(B1, conv_w_b, conv_b_b, B3, cbf, totBLD);
    gemm_mfma_dbl<<<dim3(1, M / 128, NSPLIT), blk, 0, stream>>>(cbf, DI, Wxbbf, DI, part, DI / NSPLIT);
    reduce_dbl<<<dim3((int)(NDBL / 256)), blk, 0, stream>>>(part, dblb, dtbf);
    gemm_mfma<64><<<dim3(DI / 64, M / 64), blk, 0, stream>>>(dtbf, RR, Wdtbbf, RR, 0, B1, DI, RR);
    scan_chunk<<<chunkGrid, blk, 0, stream>>>(B3, B1, bdt_b, dblb, A_log_b, Dvec_b, Pbuf, Sbuf);
    scan_combine<<<dim3(B_ * NS * DI / 256), blk, 0, stream>>>(Pbuf, Sbuf);
    scan_apply<<<applyGrid, blk, 0, stream>>>(B3, B1, dblb, A_log_b, Pbuf);

    // ---- combine ----
    // z = a @ Wi[DI:2*DI].T -> B1 (cd_b dead)
    gemm_mfma<128><<<dim3(DI / 64, M / 128), blk, 0, stream>>>(abf, DM, Wibf, DM, DI, B1, DI, DM);
    combine_rms<<<dim3(M), blk, 0, stream>>>(B2, B3, B1, nw, gbf);
    gemm_mfma<64><<<dim3(DM / 64, M / 64), blk, 0, stream>>>(gbf, DI, Wobf, DI, 0, out, DM, DI);
}